// Round 2
// baseline (235.583 us; speedup 1.0000x reference)
//
#include <hip/hip_runtime.h>
#include <stdint.h>

// Shapes are fixed by the reference: B=2, T=2048, C=1024, H=16, Dh=64.
#define B_   2
#define T_   2048
#define C_   1024
#define H_   16
#define BT   4096      // B_*T_
#define KDIM 1024      // inner dim of all projections

typedef unsigned short u16;
typedef __attribute__((ext_vector_type(8))) __bf16 bf16v8;   // 4 VGPR MFMA operand
typedef __attribute__((ext_vector_type(4))) float f32x4;     // MFMA accumulator

#define MFMA16(a, b, c) __builtin_amdgcn_mfma_f32_16x16x32_bf16((a), (b), (c), 0, 0, 0)

#define BARRIER() do { asm volatile("" ::: "memory"); \
                       __builtin_amdgcn_s_barrier();  \
                       asm volatile("" ::: "memory"); } while (0)

__device__ __forceinline__ u16 f2bf(float f) {
  __bf16 h = (__bf16)f;                       // native v_cvt (RNE)
  union { __bf16 h; u16 u; } v; v.h = h;
  return v.u;
}

// async global->LDS, 16B per lane; LDS dest is wave-uniform base + lane*16
__device__ __forceinline__ void gload16(const void* g, void* l) {
  __builtin_amdgcn_global_load_lds((__attribute__((address_space(1))) void*)g,
                                   (__attribute__((address_space(3))) void*)l,
                                   16, 0, 0);
}

// ---------------------------------------------------------------- fp32->bf16
__global__ __launch_bounds__(256) void cvt_f32_bf16(const float* __restrict__ in,
                                                    u16* __restrict__ out, int n) {
  int i = (blockIdx.x * 256 + threadIdx.x) * 4;
  if (i + 3 < n) {
    float4 v = *(const float4*)(in + i);
    ushort4 o;
    o.x = f2bf(v.x); o.y = f2bf(v.y); o.z = f2bf(v.z); o.w = f2bf(v.w);
    *(ushort4*)(out + i) = o;
  }
}

// all four 1024x1024 weight matrices in one launch
__global__ __launch_bounds__(256) void cvt_weights(
    const float* __restrict__ wq, const float* __restrict__ wk,
    const float* __restrict__ wv, const float* __restrict__ wo,
    u16* __restrict__ qkv_dst, u16* __restrict__ o_dst) {
  const int bid = blockIdx.x;          // 0..4095
  const int sel = bid >> 10;
  const float* src = (sel == 0) ? wq : (sel == 1) ? wk : (sel == 2) ? wv : wo;
  u16* dst = (sel < 3) ? (qkv_dst + sel * 1048576) : o_dst;
  const int i = ((bid & 1023) * 256 + threadIdx.x) * 4;
  float4 v = *(const float4*)(src + i);
  ushort4 o;
  o.x = f2bf(v.x); o.y = f2bf(v.y); o.z = f2bf(v.z); o.w = f2bf(v.w);
  *(ushort4*)(dst + i) = o;
}

// ---------------------------------------------------------------- GEMM (bt)
// C[M,N] = A[M,K] * Bm[N,K]^T.  M=4096, K=1024 fixed. 128x128 tile, BK=32,
// 4 waves, each wave owns a 64x64 quadrant as 4x4 16x16 fragments.
// EPI=0: write fp32 C.  EPI=1: N=3072 QKV fused; apply RoPE to q/k and
// scatter to (B,H,T,64) bf16 buffers (q pre-scaled by 0.125*log2e for the
// exp2-domain softmax in attn_fwd).
template<int EPI, int NN>
__global__ __launch_bounds__(256) void gemm_bt(
    const u16* __restrict__ A, const u16* __restrict__ Bm,
    float* __restrict__ Cf,
    u16* __restrict__ qo, u16* __restrict__ ko, u16* __restrict__ vo,
    const float* __restrict__ cosT, const float* __restrict__ sinT)
{
  __shared__ __align__(16) u16 As[128 * 32];
  __shared__ __align__(16) u16 Bs[128 * 32];
  const int tid = threadIdx.x;
  const int lane = tid & 63;
  const int w = tid >> 6;
  const int wm = w >> 1, wn = w & 1;
  const int row0 = blockIdx.y * 128, col0 = blockIdx.x * 128;
  const int lmod = lane & 15, ldiv = lane >> 4;

  f32x4 acc[4][4] = {};

  for (int k0 = 0; k0 < KDIM; k0 += 32) {
    __syncthreads();   // previous tile's reads done
#pragma unroll
    for (int c = 0; c < 2; ++c) {
      const int chunk = c * 256 + tid;
      const int r = chunk >> 2, kc = chunk & 3;
      const int ldsb = (c * 256 + (tid & 192)) * 8;   // elements
      gload16(A  + (size_t)(row0 + r) * KDIM + k0 + kc * 8, As + ldsb);
      gload16(Bm + (size_t)(col0 + r) * KDIM + k0 + kc * 8, Bs + ldsb);
    }
    __syncthreads();   // drains vmcnt: tiles ready

    bf16v8 af[4], bfr[4];
#pragma unroll
    for (int mf = 0; mf < 4; ++mf)
      af[mf] = *(const bf16v8*)(As + (wm * 64 + mf * 16 + lmod) * 32 + ldiv * 8);
#pragma unroll
    for (int nf = 0; nf < 4; ++nf)
      bfr[nf] = *(const bf16v8*)(Bs + (wn * 64 + nf * 16 + lmod) * 32 + ldiv * 8);
#pragma unroll
    for (int mf = 0; mf < 4; ++mf)
#pragma unroll
      for (int nf = 0; nf < 4; ++nf)
        acc[mf][nf] = MFMA16(af[mf], bfr[nf], acc[mf][nf]);
  }

  if (EPI == 0) {
#pragma unroll
    for (int mf = 0; mf < 4; ++mf) {
      const int mbase = row0 + wm * 64 + mf * 16 + ldiv * 4;
#pragma unroll
      for (int nf = 0; nf < 4; ++nf) {
        const int n = col0 + wn * 64 + nf * 16 + lmod;
#pragma unroll
        for (int r = 0; r < 4; ++r)
          Cf[(size_t)(mbase + r) * NN + n] = acc[mf][nf][r];
      }
    }
  } else {
    const int nb = col0 + wn * 64;
    const int proj = nb >> 10;            // 0=q 1=k 2=v
    const int hh = (nb & 1023) >> 6;      // head
    u16* dst = (proj == 0) ? qo : (proj == 1) ? ko : vo;
#pragma unroll
    for (int mf = 0; mf < 4; ++mf) {
#pragma unroll
      for (int r = 0; r < 4; ++r) {
        const int m = row0 + wm * 64 + mf * 16 + ldiv * 4 + r;
        const int b = m >> 11, t = m & 2047;
        u16* drow = dst + ((size_t)(b * H_ + hh) * T_ + t) * 64;
#pragma unroll
        for (int nf = 0; nf < 4; ++nf) {
          const int d = nf * 16 + lmod;
          float val = acc[mf][nf][r];
          if (proj < 2) {
            const float cs = cosT[t * 64 + d];
            const float sn = sinT[t * 64 + d];
            const float other = (nf < 2) ? acc[mf][nf + 2][r] : acc[mf][nf - 2][r];
            val = (nf < 2) ? (val * cs - other * sn) : (val * cs + other * sn);
            if (proj == 0) val *= 0.18033688011112042f;  // 0.125 * log2(e)
          }
          drow[d] = f2bf(val);
        }
      }
    }
  }
}

// ---------------------------------------------------------------- V -> V^T
__global__ __launch_bounds__(256) void transpose_v(const u16* __restrict__ v,
                                                   u16* __restrict__ vt) {
  __shared__ __align__(16) u16 tile[64][72];
  const int bh = blockIdx.x >> 5;
  const int tb = (blockIdx.x & 31) << 6;
  const int tid = threadIdx.x;
#pragma unroll
  for (int c = 0; c < 2; ++c) {
    const int idx = c * 256 + tid;
    const int r = idx >> 3, col = (idx & 7) << 3;
    *(uint4*)&tile[r][col] = *(const uint4*)&v[((size_t)bh * T_ + tb + r) * 64 + col];
  }
  __syncthreads();
#pragma unroll
  for (int c = 0; c < 2; ++c) {
    const int idx = c * 256 + tid;
    const int d = idx >> 3, col = (idx & 7) << 3;
    u16 tmp[8];
#pragma unroll
    for (int j = 0; j < 8; ++j) tmp[j] = tile[col + j][d];
    *(uint4*)&vt[((size_t)bh * 64 + d) * T_ + tb + col] = *(uint4*)tmp;
  }
}

// ---------------------------------------------------------------- attention
// One block = (b,h, 64 q-rows). 4 waves x 16 q-rows. Double-buffered KV tiles
// (64 keys) with counted vmcnt(4): next tile's global_load_lds stay in flight
// across the barrier (T3/T4 2-phase). Softmax in exp2 domain (Q pre-scaled);
// row sums via ones-MFMA into an f32x4 in O-accumulator layout; defer-max
// (THR = 8*log2e) skips the rescale pass on most tiles.
__global__ __launch_bounds__(256) void attn_fwd(
    const u16* __restrict__ Q, const u16* __restrict__ K,
    const u16* __restrict__ Vt, u16* __restrict__ O)
{
  __shared__ __align__(16) u16 Kl[2][64 * 64];
  __shared__ __align__(16) u16 Vl[2][64 * 64];
  __shared__ __align__(16) u16 Pl[4][16][72];
  const int bi = blockIdx.x;
  const int bh = bi >> 5;
  const int qb = 31 - (bi & 31);          // heavy q-blocks dispatch first
  const int q0 = qb << 6;
  const int tid = threadIdx.x, lane = tid & 63, w = tid >> 6;
  const int lmod = lane & 15, ldiv = lane >> 4;
  const int qrow = q0 + w * 16;

  bf16v8 aq[2];
  {
    const u16* qp = Q + ((size_t)bh * T_ + qrow + lmod) * 64;
    aq[0] = *(const bf16v8*)(qp + ldiv * 8);
    aq[1] = *(const bf16v8*)(qp + 32 + ldiv * 8);
  }
  bf16v8 onesb;
#pragma unroll
  for (int j = 0; j < 8; ++j) onesb[j] = (__bf16)1.0f;

  float m2[4] = {-1e30f, -1e30f, -1e30f, -1e30f};   // running max, log2 domain
  f32x4 lacc = {};                                   // row sums (col-replicated)
  f32x4 oacc[4] = {};

  const int nblk = qb + 1;

  auto stage = [&](int buf, int sb) {
    const int s0 = sb << 6;
#pragma unroll
    for (int c = 0; c < 2; ++c) {
      const int chunk = c * 256 + tid;
      const int r = chunk >> 3;
      const int pb = ((chunk & 7) * 16) ^ ((r & 7) << 4);   // inverse XOR swizzle
      const int ldsb = (c * 256 + (tid & 192)) * 16;        // bytes
      gload16((const char*)(K  + ((size_t)bh * T_ + s0 + r) * 64) + pb, (char*)Kl[buf] + ldsb);
      gload16((const char*)(Vt + ((size_t)(bh * 64 + r)) * T_ + s0) + pb, (char*)Vl[buf] + ldsb);
    }
  };

  stage(0, 0);
  for (int sb = 0; sb < nblk; ++sb) {
    const int cur = sb & 1;
    if (sb + 1 < nblk) {
      stage(cur ^ 1, sb + 1);                               // 4 more loads in flight
      asm volatile("s_waitcnt vmcnt(4)" ::: "memory");      // tile sb's 4 done
    } else {
      asm volatile("s_waitcnt vmcnt(0)" ::: "memory");
    }
    BARRIER();                        // tile sb visible to all waves
    const int s0 = sb << 6;
    if (s0 <= qrow + 15) {            // wave has unmasked rows in this tile
      // S = Q K^T, already in log2 domain (Q pre-scaled by 0.125*log2e)
      f32x4 sacc[4] = {};
#pragma unroll
      for (int kc = 0; kc < 2; ++kc) {
#pragma unroll
        for (int nf = 0; nf < 4; ++nf) {
          const int rr = nf * 16 + lmod;
          const int cb = (kc * 32 + ldiv * 8) * 2;
          const bf16v8 bk = *(const bf16v8*)((const char*)Kl[cur] + rr * 128 + (cb ^ ((rr & 7) << 4)));
          sacc[nf] = MFMA16(aq[kc], bk, sacc[nf]);
        }
      }
      if (s0 + 63 > qrow) {           // diagonal tile only: causal mask
#pragma unroll
        for (int nf = 0; nf < 4; ++nf) {
          const int scol = s0 + nf * 16 + lmod;
#pragma unroll
          for (int r = 0; r < 4; ++r)
            if (scol > qrow + ldiv * 4 + r) sacc[nf][r] = -1e30f;
        }
      }
      // per-row max (rows live in 16 lmod lanes x 4 frags)
      float pmax[4];
#pragma unroll
      for (int r = 0; r < 4; ++r) {
        float mx = fmaxf(fmaxf(sacc[0][r], sacc[1][r]), fmaxf(sacc[2][r], sacc[3][r]));
        mx = fmaxf(mx, __shfl_xor(mx, 1));
        mx = fmaxf(mx, __shfl_xor(mx, 2));
        mx = fmaxf(mx, __shfl_xor(mx, 4));
        mx = fmaxf(mx, __shfl_xor(mx, 8));
        pmax[r] = mx;
      }
      const bool defer = __all(pmax[0] <= m2[0] + 11.5416f &&
                               pmax[1] <= m2[1] + 11.5416f &&
                               pmax[2] <= m2[2] + 11.5416f &&
                               pmax[3] <= m2[3] + 11.5416f);
      if (!defer) {
#pragma unroll
        for (int r = 0; r < 4; ++r) {
          const float mnew = fmaxf(m2[r], pmax[r]);
          const float rs = exp2f(m2[r] - mnew);
          m2[r] = mnew;
          lacc[r] *= rs;
#pragma unroll
          for (int nf = 0; nf < 4; ++nf) oacc[nf][r] *= rs;
        }
      }
      // P = exp2(S - m2) -> per-wave LDS (C-layout) -> A-layout fragments
#pragma unroll
      for (int nf = 0; nf < 4; ++nf)
#pragma unroll
        for (int r = 0; r < 4; ++r)
          Pl[w][ldiv * 4 + r][nf * 16 + lmod] = f2bf(exp2f(sacc[nf][r] - m2[r]));
      bf16v8 ap0 = *(const bf16v8*)&Pl[w][lmod][ldiv * 8];
      bf16v8 ap1 = *(const bf16v8*)&Pl[w][lmod][32 + ldiv * 8];
      // O += P V ; row-sums += P * ones (same accumulator layout)
#pragma unroll
      for (int kc = 0; kc < 2; ++kc) {
        const bf16v8 ap = (kc == 0) ? ap0 : ap1;
#pragma unroll
        for (int nf = 0; nf < 4; ++nf) {
          const int rr = nf * 16 + lmod;
          const int cb = (kc * 32 + ldiv * 8) * 2;
          const bf16v8 bv = *(const bf16v8*)((const char*)Vl[cur] + rr * 128 + (cb ^ ((rr & 7) << 4)));
          oacc[nf] = MFMA16(ap, bv, oacc[nf]);
        }
        lacc = MFMA16(ap, onesb, lacc);
      }
    }
    BARRIER();                        // all waves done reading buf[cur]
  }

  const int b = bh >> 4, hh = bh & 15;
#pragma unroll
  for (int r = 0; r < 4; ++r) {
    const int t = qrow + ldiv * 4 + r;
    const float inv = 1.f / lacc[r];
    u16* orow = O + ((size_t)(b * T_ + t)) * C_ + hh * 64;
#pragma unroll
    for (int nf = 0; nf < 4; ++nf)
      orow[nf * 16 + lmod] = f2bf(oacc[nf][r] * inv);
  }
}

// ---------------------------------------------------------------- launch
extern "C" void kernel_launch(void* const* d_in, const int* in_sizes, int n_in,
                              void* d_out, int out_size, void* d_ws, size_t ws_size,
                              hipStream_t stream) {
  const float* x    = (const float*)d_in[0];
  const float* cosT = (const float*)d_in[1];
  const float* sinT = (const float*)d_in[2];
  // d_in[3] = mask (causal by construction, unused), d_in[4] = n_heads (=16)
  const float* Wq = (const float*)d_in[5];
  const float* Wk = (const float*)d_in[6];
  const float* Wv = (const float*)d_in[7];
  const float* Wo = (const float*)d_in[8];
  float* out = (float*)d_out;

  // workspace layout (48 MB total)
  char* ws = (char*)d_ws;
  u16* xb   = (u16*)(ws);                    // bf16 x (later reused as attn_out)
  u16* wqkv = (u16*)(ws + 8388608);          // [Wq;Wk;Wv] bf16
  u16* wo   = (u16*)(ws + 14680064);         // Wo bf16
  u16* q    = (u16*)(ws + 16777216);         // (B,H,T,64) bf16, roped+scaled
  u16* k    = (u16*)(ws + 25165824);         // (B,H,T,64) bf16, roped
  u16* v    = (u16*)(ws + 33554432);         // (B,H,T,64) bf16
  u16* vt   = (u16*)(ws + 41943040);         // (B,H,64,T) bf16
  u16* aout = xb;                            // attention output reuses xb slot

  cvt_f32_bf16<<<4096, 256, 0, stream>>>(x, xb, BT * C_);
  cvt_weights<<<4096, 256, 0, stream>>>(Wq, Wk, Wv, Wo, wqkv, wo);

  gemm_bt<1, 3072><<<dim3(24, 32), 256, 0, stream>>>(xb, wqkv, nullptr,
                                                     q, k, v, cosT, sinT);
  transpose_v<<<1024, 256, 0, stream>>>(v, vt);
  attn_fwd<<<1024, 256, 0, stream>>>(q, k, vt, aout);
  gemm_bt<0, 1024><<<dim3(8, 32), 256, 0, stream>>>(aout, wo, out,
                                                    nullptr, nullptr, nullptr,
                                                    nullptr, nullptr);
}

// Round 3
// 188.144 us; speedup vs baseline: 1.2521x; 1.2521x over previous
//
#include <hip/hip_runtime.h>
#include <stdint.h>

// Shapes are fixed by the reference: B=2, T=2048, C=1024, H=16, Dh=64.
#define B_   2
#define T_   2048
#define C_   1024
#define H_   16
#define BT   4096      // B_*T_
#define KDIM 1024      // inner dim of all projections

typedef unsigned short u16;
typedef __attribute__((ext_vector_type(8))) __bf16 bf16v8;   // 4 VGPR MFMA operand
typedef __attribute__((ext_vector_type(4))) float f32x4;     // 16x16 accumulator
typedef __attribute__((ext_vector_type(16))) float f32x16;   // 32x32 accumulator
typedef __attribute__((ext_vector_type(4))) unsigned int u32x4;

#define MFMA16(a, b, c) __builtin_amdgcn_mfma_f32_16x16x32_bf16((a), (b), (c), 0, 0, 0)
#define MFMA32(a, b, c) __builtin_amdgcn_mfma_f32_32x32x16_bf16((a), (b), (c), 0, 0, 0)

__device__ __forceinline__ u16 f2bf(float f) {
  __bf16 h = (__bf16)f;                       // native v_cvt (RNE)
  union { __bf16 h; u16 u; } v; v.h = h;
  return v.u;
}

// async global->LDS, 16B per lane; LDS dest is wave-uniform base + lane*16
__device__ __forceinline__ void gload16(const void* g, void* l) {
  __builtin_amdgcn_global_load_lds((__attribute__((address_space(1))) void*)g,
                                   (__attribute__((address_space(3))) void*)l,
                                   16, 0, 0);
}

// ---------------------------------------------------------------- fp32->bf16
__global__ __launch_bounds__(256) void cvt_f32_bf16(const float* __restrict__ in,
                                                    u16* __restrict__ out, int n) {
  int i = (blockIdx.x * 256 + threadIdx.x) * 4;
  if (i + 3 < n) {
    float4 v = *(const float4*)(in + i);
    ushort4 o;
    o.x = f2bf(v.x); o.y = f2bf(v.y); o.z = f2bf(v.z); o.w = f2bf(v.w);
    *(ushort4*)(out + i) = o;
  }
}

// all four 1024x1024 weight matrices in one launch
__global__ __launch_bounds__(256) void cvt_weights(
    const float* __restrict__ wq, const float* __restrict__ wk,
    const float* __restrict__ wv, const float* __restrict__ wo,
    u16* __restrict__ qkv_dst, u16* __restrict__ o_dst) {
  const int bid = blockIdx.x;          // 0..4095
  const int sel = bid >> 10;
  const float* src = (sel == 0) ? wq : (sel == 1) ? wk : (sel == 2) ? wv : wo;
  u16* dst = (sel < 3) ? (qkv_dst + sel * 1048576) : o_dst;
  const int i = ((bid & 1023) * 256 + threadIdx.x) * 4;
  float4 v = *(const float4*)(src + i);
  ushort4 o;
  o.x = f2bf(v.x); o.y = f2bf(v.y); o.z = f2bf(v.z); o.w = f2bf(v.w);
  *(ushort4*)(dst + i) = o;
}

// ---------------------------------------------------------------- GEMM (bt)
// C[M,N] = A[M,K] * Bm[N,K]^T.  M=4096, K=1024 fixed. 128x128 tile, BK=32,
// 4 waves, each wave owns a 64x64 quadrant as 4x4 16x16 fragments.
// EPI=0: write fp32 C.  EPI=1: N=3072 QKV fused; apply RoPE to q/k and
// scatter to (B,H,T,64) bf16 buffers (q pre-scaled by 0.125*log2e for the
// exp2-domain softmax in attn_fwd2).
template<int EPI, int NN>
__global__ __launch_bounds__(256) void gemm_bt(
    const u16* __restrict__ A, const u16* __restrict__ Bm,
    float* __restrict__ Cf,
    u16* __restrict__ qo, u16* __restrict__ ko, u16* __restrict__ vo,
    const float* __restrict__ cosT, const float* __restrict__ sinT)
{
  __shared__ __align__(16) u16 As[128 * 32];
  __shared__ __align__(16) u16 Bs[128 * 32];
  const int tid = threadIdx.x;
  const int lane = tid & 63;
  const int w = tid >> 6;
  const int wm = w >> 1, wn = w & 1;
  const int row0 = blockIdx.y * 128, col0 = blockIdx.x * 128;
  const int lmod = lane & 15, ldiv = lane >> 4;

  f32x4 acc[4][4] = {};

  for (int k0 = 0; k0 < KDIM; k0 += 32) {
    __syncthreads();   // previous tile's reads done
#pragma unroll
    for (int c = 0; c < 2; ++c) {
      const int chunk = c * 256 + tid;
      const int r = chunk >> 2, kc = chunk & 3;
      const int ldsb = (c * 256 + (tid & 192)) * 8;   // elements
      gload16(A  + (size_t)(row0 + r) * KDIM + k0 + kc * 8, As + ldsb);
      gload16(Bm + (size_t)(col0 + r) * KDIM + k0 + kc * 8, Bs + ldsb);
    }
    __syncthreads();   // drains vmcnt: tiles ready

    bf16v8 af[4], bfr[4];
#pragma unroll
    for (int mf = 0; mf < 4; ++mf)
      af[mf] = *(const bf16v8*)(As + (wm * 64 + mf * 16 + lmod) * 32 + ldiv * 8);
#pragma unroll
    for (int nf = 0; nf < 4; ++nf)
      bfr[nf] = *(const bf16v8*)(Bs + (wn * 64 + nf * 16 + lmod) * 32 + ldiv * 8);
#pragma unroll
    for (int mf = 0; mf < 4; ++mf)
#pragma unroll
      for (int nf = 0; nf < 4; ++nf)
        acc[mf][nf] = MFMA16(af[mf], bfr[nf], acc[mf][nf]);
  }

  if (EPI == 0) {
#pragma unroll
    for (int mf = 0; mf < 4; ++mf) {
      const int mbase = row0 + wm * 64 + mf * 16 + ldiv * 4;
#pragma unroll
      for (int nf = 0; nf < 4; ++nf) {
        const int n = col0 + wn * 64 + nf * 16 + lmod;
#pragma unroll
        for (int r = 0; r < 4; ++r)
          Cf[(size_t)(mbase + r) * NN + n] = acc[mf][nf][r];
      }
    }
  } else {
    const int nb = col0 + wn * 64;
    const int proj = nb >> 10;            // 0=q 1=k 2=v
    const int hh = (nb & 1023) >> 6;      // head
    u16* dst = (proj == 0) ? qo : (proj == 1) ? ko : vo;
#pragma unroll
    for (int mf = 0; mf < 4; ++mf) {
#pragma unroll
      for (int r = 0; r < 4; ++r) {
        const int m = row0 + wm * 64 + mf * 16 + ldiv * 4 + r;
        const int b = m >> 11, t = m & 2047;
        u16* drow = dst + ((size_t)(b * H_ + hh) * T_ + t) * 64;
#pragma unroll
        for (int nf = 0; nf < 4; ++nf) {
          const int d = nf * 16 + lmod;
          float val = acc[mf][nf][r];
          if (proj < 2) {
            const float cs = cosT[t * 64 + d];
            const float sn = sinT[t * 64 + d];
            const float other = (nf < 2) ? acc[mf][nf + 2][r] : acc[mf][nf - 2][r];
            val = (nf < 2) ? (val * cs - other * sn) : (val * cs + other * sn);
            if (proj == 0) val *= 0.18033688011112042f;  // 0.125 * log2(e)
          }
          drow[d] = f2bf(val);
        }
      }
    }
  }
}

// ---------------------------------------------------------------- V -> V^T
// v (BH, T, 64) -> vt (BH, 64, T)
__global__ __launch_bounds__(256) void transpose_v(const u16* __restrict__ v,
                                                   u16* __restrict__ vt) {
  __shared__ __align__(16) u16 tile[64][72];
  const int bh = blockIdx.x >> 5;
  const int tb = (blockIdx.x & 31) << 6;
  const int tid = threadIdx.x;
#pragma unroll
  for (int c = 0; c < 2; ++c) {
    const int idx = c * 256 + tid;
    const int r = idx >> 3, col = (idx & 7) << 3;
    *(uint4*)&tile[r][col] = *(const uint4*)&v[((size_t)bh * T_ + tb + r) * 64 + col];
  }
  __syncthreads();
#pragma unroll
  for (int c = 0; c < 2; ++c) {
    const int idx = c * 256 + tid;
    const int d = idx >> 3, col = (idx & 7) << 3;
    u16 tmp[8];
#pragma unroll
    for (int j = 0; j < 8; ++j) tmp[j] = tile[col + j][d];
    *(uint4*)&vt[((size_t)bh * 64 + d) * T_ + tb + col] = *(uint4*)tmp;
  }
}

// ---------------------------------------------------------------- O^T -> O
// ot (BH, 64, T) -> o (B, T, C) with head offset
__global__ __launch_bounds__(256) void transpose_o(const u16* __restrict__ src,
                                                   u16* __restrict__ dst) {
  __shared__ __align__(16) u16 tile[64][72];
  const int bh = blockIdx.x >> 5;
  const int tb = (blockIdx.x & 31) << 6;
  const int tid = threadIdx.x;
#pragma unroll
  for (int c = 0; c < 2; ++c) {
    const int idx = c * 256 + tid;
    const int d = idx >> 3, col = (idx & 7) << 3;       // [d][t]
    *(uint4*)&tile[d][col] = *(const uint4*)&src[((size_t)bh * 64 + d) * T_ + tb + col];
  }
  __syncthreads();
  const int b = bh >> 4, hh = bh & 15;
#pragma unroll
  for (int c = 0; c < 2; ++c) {
    const int idx = c * 256 + tid;
    const int t = idx >> 3, col = (idx & 7) << 3;
    u16 tmp[8];
#pragma unroll
    for (int j = 0; j < 8; ++j) tmp[j] = tile[col + j][t];
    *(uint4*)&dst[((size_t)(b * T_ + tb + t)) * C_ + hh * 64 + col] = *(uint4*)tmp;
  }
}

// ---------------------------------------------------------------- attention
// Zero-LDS, zero-barrier flash attention. One wave = one 32-q-row tile of one
// (b,h). Swapped QK^T: S^T = mfma32(K, Q) puts q=lane&31, keys lane-local in
// 16 regs -> softmax is in-lane + one shfl_xor(32). P re-fragmented in-register
// (cvt_pk_bf16 + shfl_xor(32) + cndmask). O accumulated transposed:
// O^T = mfma32(V^T, P) so cols = q -> per-lane scalar m/l/rescale. K/V frags
// are direct 16B global loads (L2-resident per XCD via bh swizzle), 1-tile
// register prefetch. Waves w and w+4 (same SIMD) get light+heavy qtiles
// summing to a uniform 65 tiles per SIMD.
__global__ __launch_bounds__(512, 2) void attn_fwd2(
    const u16* __restrict__ Q, const u16* __restrict__ K,
    const u16* __restrict__ Vt, u16* __restrict__ Ot)
{
  const int b = blockIdx.x;                        // 256 blocks
  const int bh = (b & 7) * 4 + ((b >> 3) & 3);     // 4 bh per XCD (b%8)
  const int g  = b >> 5;                           // 0..7
  const int tid = threadIdx.x;
  const int w = tid >> 6, lane = tid & 63;
  const int l31 = lane & 31, hi = lane >> 5;
  const int qt = (w < 4) ? (g * 4 + w) : (63 - (g * 4 + (w - 4)));
  const int q0 = qt * 32;
  const int nt = qt + 1;                           // causal: tiles 0..qt

  // Q B-fragments (held whole kernel): lane holds Q[q0+l31][kg*16+hi*8+j]
  bf16v8 qf[4];
  {
    const u16* qp = Q + ((size_t)bh * T_ + q0 + l31) * 64 + hi * 8;
    qf[0] = *(const bf16v8*)(qp);
    qf[1] = *(const bf16v8*)(qp + 16);
    qf[2] = *(const bf16v8*)(qp + 32);
    qf[3] = *(const bf16v8*)(qp + 48);
  }

  float m2 = -1e30f, lsum = 0.f;                   // log2-domain running max / sum
  f32x16 oacc0 = {}, oacc1 = {};                   // O^T d-blocks 0..31 / 32..63

  const u16* kbase = K + ((size_t)bh * T_ + l31) * 64 + hi * 8;
  const u16* vbase = Vt + ((size_t)bh * 64 + l31) * T_ + hi * 8;

  auto loadKV = [&](bf16v8 (&kf)[4], bf16v8 (&vf)[4], int t) {
    const u16* kp = kbase + (size_t)t * (32 * 64);
    kf[0] = *(const bf16v8*)(kp);
    kf[1] = *(const bf16v8*)(kp + 16);
    kf[2] = *(const bf16v8*)(kp + 32);
    kf[3] = *(const bf16v8*)(kp + 48);
    const u16* vp = vbase + t * 32;
    vf[0] = *(const bf16v8*)(vp);                  // db0, kg0
    vf[1] = *(const bf16v8*)(vp + 16);             // db0, kg1
    vf[2] = *(const bf16v8*)(vp + (size_t)32 * T_);
    vf[3] = *(const bf16v8*)(vp + (size_t)32 * T_ + 16);
  };

  auto step = [&](const bf16v8 (&kf)[4], const bf16v8 (&vf)[4], bool diag) {
    f32x16 s = {};
    s = MFMA32(kf[0], qf[0], s);
    s = MFMA32(kf[1], qf[1], s);
    s = MFMA32(kf[2], qf[2], s);
    s = MFMA32(kf[3], qf[3], s);
    if (diag) {                                    // key_local > q_local -> -inf
#pragma unroll
      for (int r = 0; r < 16; ++r) {
        const int kl = (r & 3) + 8 * (r >> 2) + 4 * hi;
        if (kl > l31) s[r] = -1e30f;
      }
    }
    float pmax = s[0];
#pragma unroll
    for (int r = 1; r < 16; ++r) pmax = fmaxf(pmax, s[r]);
    pmax = fmaxf(pmax, __shfl_xor(pmax, 32));
    if (!__all(pmax <= m2 + 11.5416f)) {           // defer-max THR = 8*log2e
      const float mnew = fmaxf(m2, pmax);
      const float rs = __builtin_amdgcn_exp2f(m2 - mnew);
      lsum *= rs;
#pragma unroll
      for (int r = 0; r < 16; ++r) { oacc0[r] *= rs; oacc1[r] *= rs; }
      m2 = mnew;
    }
    float p[16]; float ts = 0.f;
#pragma unroll
    for (int r = 0; r < 16; ++r) {
      p[r] = __builtin_amdgcn_exp2f(s[r] - m2);
      ts += p[r];
    }
    ts += __shfl_xor(ts, 32);
    lsum += ts;
    // pack P pairs: o[j] = bf16(keybase 8*(j>>1)+4hi+2*(j&1)) | bf16(+1)<<16
    uint32_t o[8];
#pragma unroll
    for (int j = 0; j < 8; ++j) {
      const int r0 = 4 * (j >> 1) + 2 * (j & 1);
      uint32_t d;
      asm("v_cvt_pk_bf16_f32 %0, %1, %2" : "=v"(d) : "v"(p[r0]), "v"(p[r0 + 1]));
      o[j] = d;
    }
    uint32_t po[8];
#pragma unroll
    for (int j = 0; j < 8; ++j) po[j] = __shfl_xor(o[j], 32);
    // B-frag for kg: slot s holds keys (16kg + 8hi + 2s, +1)
#pragma unroll
    for (int kg = 0; kg < 2; ++kg) {
      u32x4 fr;
      fr.x = hi ? po[4 * kg + 2] : o[4 * kg + 0];
      fr.y = hi ? po[4 * kg + 3] : o[4 * kg + 1];
      fr.z = hi ? o[4 * kg + 2] : po[4 * kg + 0];
      fr.w = hi ? o[4 * kg + 3] : po[4 * kg + 1];
      const bf16v8 pf = __builtin_bit_cast(bf16v8, fr);
      oacc0 = MFMA32(vf[kg], pf, oacc0);
      oacc1 = MFMA32(vf[2 + kg], pf, oacc1);
    }
  };

  bf16v8 kA[4], vA[4], kB[4], vB[4];
  loadKV(kA, vA, 0);
  int t = 0;
  while (true) {
    if (t + 1 < nt) loadKV(kB, vB, t + 1);
    step(kA, vA, t == nt - 1);
    ++t; if (t >= nt) break;
    if (t + 1 < nt) loadKV(kA, vA, t + 1);
    step(kB, vB, t == nt - 1);
    ++t; if (t >= nt) break;
  }

  const float inv = 1.f / lsum;
  u16* obase = Ot + ((size_t)bh * 64) * T_ + q0 + l31;
#pragma unroll
  for (int r = 0; r < 16; ++r) {
    const int d0 = (r & 3) + 8 * (r >> 2) + 4 * hi;
    obase[(size_t)d0 * T_]        = f2bf(oacc0[r] * inv);
    obase[(size_t)(d0 + 32) * T_] = f2bf(oacc1[r] * inv);
  }
}

// ---------------------------------------------------------------- launch
extern "C" void kernel_launch(void* const* d_in, const int* in_sizes, int n_in,
                              void* d_out, int out_size, void* d_ws, size_t ws_size,
                              hipStream_t stream) {
  const float* x    = (const float*)d_in[0];
  const float* cosT = (const float*)d_in[1];
  const float* sinT = (const float*)d_in[2];
  // d_in[3] = mask (causal by construction, unused), d_in[4] = n_heads (=16)
  const float* Wq = (const float*)d_in[5];
  const float* Wk = (const float*)d_in[6];
  const float* Wv = (const float*)d_in[7];
  const float* Wo = (const float*)d_in[8];
  float* out = (float*)d_out;

  // workspace layout (48 MB total)
  char* ws = (char*)d_ws;
  u16* xb   = (u16*)(ws);                    // bf16 x; reused as aoutT after gemm1
  u16* wqkv = (u16*)(ws + 8388608);          // [Wq;Wk;Wv] bf16
  u16* wo   = (u16*)(ws + 14680064);         // Wo bf16
  u16* q    = (u16*)(ws + 16777216);         // (B,H,T,64) bf16, roped+scaled; reused as aout
  u16* k    = (u16*)(ws + 25165824);         // (B,H,T,64) bf16, roped
  u16* v    = (u16*)(ws + 33554432);         // (B,H,T,64) bf16
  u16* vt   = (u16*)(ws + 41943040);         // (B,H,64,T) bf16
  u16* aoutT = xb;                           // attention output^T (BH,64,T)
  u16* aout  = q;                            // transposed back (B,T,C)

  cvt_f32_bf16<<<4096, 256, 0, stream>>>(x, xb, BT * C_);
  cvt_weights<<<4096, 256, 0, stream>>>(Wq, Wk, Wv, Wo, wqkv, wo);

  gemm_bt<1, 3072><<<dim3(24, 32), 256, 0, stream>>>(xb, wqkv, nullptr,
                                                     q, k, v, cosT, sinT);
  transpose_v<<<1024, 256, 0, stream>>>(v, vt);
  attn_fwd2<<<256, 512, 0, stream>>>(q, k, vt, aoutT);
  transpose_o<<<1024, 256, 0, stream>>>(aoutT, aout);
  gemm_bt<0, 1024><<<dim3(8, 32), 256, 0, stream>>>(aout, wo, out,
                                                    nullptr, nullptr, nullptr,
                                                    nullptr, nullptr);
}

// Round 4
// 173.935 us; speedup vs baseline: 1.3544x; 1.0817x over previous
//
#include <hip/hip_runtime.h>
#include <stdint.h>

// Shapes are fixed by the reference: B=2, T=2048, C=1024, H=16, Dh=64.
#define B_   2
#define T_   2048
#define C_   1024
#define H_   16
#define BT   4096      // B_*T_
#define KDIM 1024      // inner dim of all projections

typedef unsigned short u16;
typedef __attribute__((ext_vector_type(8))) __bf16 bf16v8;   // 4 VGPR MFMA operand
typedef __attribute__((ext_vector_type(4))) float f32x4;     // 16x16 accumulator
typedef __attribute__((ext_vector_type(16))) float f32x16;   // 32x32 accumulator
typedef __attribute__((ext_vector_type(4))) unsigned int u32x4;

#define MFMA16(a, b, c) __builtin_amdgcn_mfma_f32_16x16x32_bf16((a), (b), (c), 0, 0, 0)
#define MFMA32(a, b, c) __builtin_amdgcn_mfma_f32_32x32x16_bf16((a), (b), (c), 0, 0, 0)

#define BARRIER() do { asm volatile("" ::: "memory"); \
                       __builtin_amdgcn_s_barrier();  \
                       asm volatile("" ::: "memory"); } while (0)

__device__ __forceinline__ u16 f2bf(float f) {
  __bf16 h = (__bf16)f;                       // native v_cvt (RNE)
  union { __bf16 h; u16 u; } v; v.h = h;
  return v.u;
}

// async global->LDS, 16B per lane; LDS dest is wave-uniform base + lane*16
__device__ __forceinline__ void gload16(const void* g, void* l) {
  __builtin_amdgcn_global_load_lds((__attribute__((address_space(1))) void*)g,
                                   (__attribute__((address_space(3))) void*)l,
                                   16, 0, 0);
}

// ---------------------------------------------------------------- fp32->bf16
__global__ __launch_bounds__(256) void cvt_f32_bf16(const float* __restrict__ in,
                                                    u16* __restrict__ out, int n) {
  int i = (blockIdx.x * 256 + threadIdx.x) * 4;
  if (i + 3 < n) {
    float4 v = *(const float4*)(in + i);
    ushort4 o;
    o.x = f2bf(v.x); o.y = f2bf(v.y); o.z = f2bf(v.z); o.w = f2bf(v.w);
    *(ushort4*)(out + i) = o;
  }
}

// all four 1024x1024 weight matrices in one launch
__global__ __launch_bounds__(256) void cvt_weights(
    const float* __restrict__ wq, const float* __restrict__ wk,
    const float* __restrict__ wv, const float* __restrict__ wo,
    u16* __restrict__ qkv_dst, u16* __restrict__ o_dst) {
  const int bid = blockIdx.x;          // 0..4095
  const int sel = bid >> 10;
  const float* src = (sel == 0) ? wq : (sel == 1) ? wk : (sel == 2) ? wv : wo;
  u16* dst = (sel < 3) ? (qkv_dst + sel * 1048576) : o_dst;
  const int i = ((bid & 1023) * 256 + threadIdx.x) * 4;
  float4 v = *(const float4*)(src + i);
  ushort4 o;
  o.x = f2bf(v.x); o.y = f2bf(v.y); o.z = f2bf(v.z); o.w = f2bf(v.w);
  *(ushort4*)(dst + i) = o;
}

// ---------------------------------------------------------------- QKV GEMM
// C[M=4096, N=3072] = x[M,K=1024] * Wqkv[N,K]^T, fused RoPE + scatter.
// 256x256 tile, BK=64, 8 waves (2M x 4N), per-wave 128x64 output (8x4 frags).
// LDS 128 KiB: double-buffered A,B tiles, XOR-swizzled (stage source carries
// the inverse swizzle; ds_reads apply it -> conflict-free b128 reads).
// 4 role-split phases per K-tile; next tile's 8 global_load_lds issued at
// phase 0 (4-phase lead), single vmcnt(0) drain before the tile's last barrier.
__global__ __launch_bounds__(512, 2) void gemm_qkv256(
    const u16* __restrict__ A, const u16* __restrict__ Bm,
    u16* __restrict__ qo, u16* __restrict__ ko, u16* __restrict__ vo,
    const float* __restrict__ cosT, const float* __restrict__ sinT)
{
  __shared__ __align__(16) u16 As[2][256 * 64];   // 64 KiB
  __shared__ __align__(16) u16 Bs[2][256 * 64];   // 64 KiB
  const int tid = threadIdx.x;
  const int lane = tid & 63;
  const int w = tid >> 6;                 // 0..7
  const int wm = w >> 2, wn = w & 3;      // 2 x 4 wave grid
  const int lmod = lane & 15, ldiv = lane >> 4;

  // XCD-aware swizzle: grid 192 = 8 XCDs x 24; each XCD gets 2 full by-rows
  const int nbx = 3072 / 256;             // 12
  const int swz = (blockIdx.x & 7) * 24 + (blockIdx.x >> 3);
  const int bx = swz % nbx, by = swz / nbx;
  const int row0 = by * 256, col0 = bx * 256;

  // stage: 8 chunks of 8KB (4 A + 4 B); thread -> row = c*64 + tid/8,
  // 16B col = (tid&7)*16, source pre-XOR-swizzled by ((row&7)<<4)
  const int srow = tid >> 3;
  const int scol = (tid & 7) * 16;
  const int sswz = scol ^ ((srow & 7) << 4);
  const char* Ab = (const char*)A + (size_t)(row0 + srow) * (KDIM * 2) + sswz;
  const char* Bb = (const char*)Bm + (size_t)(col0 + srow) * (KDIM * 2) + sswz;
  auto loadTile = [&](int buf, int v) {
    const int kb = v * 128;               // byte offset of K-tile
#pragma unroll
    for (int c = 0; c < 4; ++c)
      gload16(Ab + (size_t)c * 64 * (KDIM * 2) + kb,
              (char*)As[buf] + c * 8192 + w * 1024);
#pragma unroll
    for (int c = 0; c < 4; ++c)
      gload16(Bb + (size_t)c * 64 * (KDIM * 2) + kb,
              (char*)Bs[buf] + c * 8192 + w * 1024);
  };

  f32x4 acc[8][4] = {};

  loadTile(0, 0);
  asm volatile("s_waitcnt vmcnt(0)" ::: "memory");
  BARRIER();

  for (int v = 0; v < 16; ++v) {
    const int bb = v & 1;
    bf16v8 bfr[4][2];
#pragma unroll
    for (int p = 0; p < 4; ++p) {
      // ds-reads for this phase (B once at p0, A quadrant每 phase)
      if (p == 0) {
#pragma unroll
        for (int nf = 0; nf < 4; ++nf) {
          const int rr = wn * 64 + nf * 16 + lmod;
#pragma unroll
          for (int kc = 0; kc < 2; ++kc)
            bfr[nf][kc] = *(const bf16v8*)((const char*)Bs[bb] + rr * 128 +
                              ((kc * 64 + ldiv * 16) ^ ((rr & 7) << 4)));
        }
      }
      bf16v8 af[2][2];
#pragma unroll
      for (int i = 0; i < 2; ++i) {
        const int rr = wm * 128 + (2 * p + i) * 16 + lmod;
#pragma unroll
        for (int kc = 0; kc < 2; ++kc)
          af[i][kc] = *(const bf16v8*)((const char*)As[bb] + rr * 128 +
                            ((kc * 64 + ldiv * 16) ^ ((rr & 7) << 4)));
      }
      if (p == 0 && v + 1 < 16) loadTile(bb ^ 1, v + 1);   // 4-phase lead
      BARRIER();                       // role-split: all reads issued
      __builtin_amdgcn_s_setprio(1);
#pragma unroll
      for (int i = 0; i < 2; ++i)
#pragma unroll
        for (int nf = 0; nf < 4; ++nf)
#pragma unroll
          for (int kc = 0; kc < 2; ++kc)
            acc[2 * p + i][nf] = MFMA16(af[i][kc], bfr[nf][kc], acc[2 * p + i][nf]);
      __builtin_amdgcn_s_setprio(0);
      if (p == 3 && v + 1 < 16)
        asm volatile("s_waitcnt vmcnt(0)" ::: "memory");   // next tile landed
      BARRIER();                       // phase closed
    }
  }

  // epilogue: RoPE + scatter (wave's 64-col block is one head)
  const int nb = col0 + wn * 64;
  const int proj = nb >> 10;            // 0=q 1=k 2=v
  const int hh = (nb & 1023) >> 6;      // head
  u16* dst = (proj == 0) ? qo : (proj == 1) ? ko : vo;
#pragma unroll
  for (int mf = 0; mf < 8; ++mf) {
#pragma unroll
    for (int r = 0; r < 4; ++r) {
      const int m = row0 + wm * 128 + mf * 16 + ldiv * 4 + r;
      const int b = m >> 11, t = m & 2047;
      u16* drow = dst + ((size_t)(b * H_ + hh) * T_ + t) * 64;
#pragma unroll
      for (int nf = 0; nf < 4; ++nf) {
        const int d = nf * 16 + lmod;
        float val = acc[mf][nf][r];
        if (proj < 2) {
          const float cs = cosT[t * 64 + d];
          const float sn = sinT[t * 64 + d];
          const float other = (nf < 2) ? acc[mf][nf + 2][r] : acc[mf][nf - 2][r];
          val = (nf < 2) ? (val * cs - other * sn) : (val * cs + other * sn);
          if (proj == 0) val *= 0.18033688011112042f;  // 0.125 * log2(e)
        }
        drow[d] = f2bf(val);
      }
    }
  }
}

// ---------------------------------------------------------------- GEMM (bt)
// m97-style 128x128 tile; used for the output projection (N=1024).
template<int EPI, int NN>
__global__ __launch_bounds__(256) void gemm_bt(
    const u16* __restrict__ A, const u16* __restrict__ Bm,
    float* __restrict__ Cf)
{
  __shared__ __align__(16) u16 As[128 * 32];
  __shared__ __align__(16) u16 Bs[128 * 32];
  const int tid = threadIdx.x;
  const int lane = tid & 63;
  const int w = tid >> 6;
  const int wm = w >> 1, wn = w & 1;
  const int row0 = blockIdx.y * 128, col0 = blockIdx.x * 128;
  const int lmod = lane & 15, ldiv = lane >> 4;

  f32x4 acc[4][4] = {};

  for (int k0 = 0; k0 < KDIM; k0 += 32) {
    __syncthreads();   // previous tile's reads done
#pragma unroll
    for (int c = 0; c < 2; ++c) {
      const int chunk = c * 256 + tid;
      const int r = chunk >> 2, kc = chunk & 3;
      const int ldsb = (c * 256 + (tid & 192)) * 8;   // elements
      gload16(A  + (size_t)(row0 + r) * KDIM + k0 + kc * 8, As + ldsb);
      gload16(Bm + (size_t)(col0 + r) * KDIM + k0 + kc * 8, Bs + ldsb);
    }
    __syncthreads();   // drains vmcnt: tiles ready

    bf16v8 af[4], bfr[4];
#pragma unroll
    for (int mf = 0; mf < 4; ++mf)
      af[mf] = *(const bf16v8*)(As + (wm * 64 + mf * 16 + lmod) * 32 + ldiv * 8);
#pragma unroll
    for (int nf = 0; nf < 4; ++nf)
      bfr[nf] = *(const bf16v8*)(Bs + (wn * 64 + nf * 16 + lmod) * 32 + ldiv * 8);
#pragma unroll
    for (int mf = 0; mf < 4; ++mf)
#pragma unroll
      for (int nf = 0; nf < 4; ++nf)
        acc[mf][nf] = MFMA16(af[mf], bfr[nf], acc[mf][nf]);
  }

#pragma unroll
  for (int mf = 0; mf < 4; ++mf) {
    const int mbase = row0 + wm * 64 + mf * 16 + ldiv * 4;
#pragma unroll
    for (int nf = 0; nf < 4; ++nf) {
      const int n = col0 + wn * 64 + nf * 16 + lmod;
#pragma unroll
      for (int r = 0; r < 4; ++r)
        Cf[(size_t)(mbase + r) * NN + n] = acc[mf][nf][r];
    }
  }
}

// ---------------------------------------------------------------- V -> V^T
// v (BH, T, 64) -> vt (BH, 64, T)
__global__ __launch_bounds__(256) void transpose_v(const u16* __restrict__ v,
                                                   u16* __restrict__ vt) {
  __shared__ __align__(16) u16 tile[64][72];
  const int bh = blockIdx.x >> 5;
  const int tb = (blockIdx.x & 31) << 6;
  const int tid = threadIdx.x;
#pragma unroll
  for (int c = 0; c < 2; ++c) {
    const int idx = c * 256 + tid;
    const int r = idx >> 3, col = (idx & 7) << 3;
    *(uint4*)&tile[r][col] = *(const uint4*)&v[((size_t)bh * T_ + tb + r) * 64 + col];
  }
  __syncthreads();
#pragma unroll
  for (int c = 0; c < 2; ++c) {
    const int idx = c * 256 + tid;
    const int d = idx >> 3, col = (idx & 7) << 3;
    u16 tmp[8];
#pragma unroll
    for (int j = 0; j < 8; ++j) tmp[j] = tile[col + j][d];
    *(uint4*)&vt[((size_t)bh * 64 + d) * T_ + tb + col] = *(uint4*)tmp;
  }
}

// ---------------------------------------------------------------- O^T -> O
__global__ __launch_bounds__(256) void transpose_o(const u16* __restrict__ src,
                                                   u16* __restrict__ dst) {
  __shared__ __align__(16) u16 tile[64][72];
  const int bh = blockIdx.x >> 5;
  const int tb = (blockIdx.x & 31) << 6;
  const int tid = threadIdx.x;
#pragma unroll
  for (int c = 0; c < 2; ++c) {
    const int idx = c * 256 + tid;
    const int d = idx >> 3, col = (idx & 7) << 3;       // [d][t]
    *(uint4*)&tile[d][col] = *(const uint4*)&src[((size_t)bh * 64 + d) * T_ + tb + col];
  }
  __syncthreads();
  const int b = bh >> 4, hh = bh & 15;
#pragma unroll
  for (int c = 0; c < 2; ++c) {
    const int idx = c * 256 + tid;
    const int t = idx >> 3, col = (idx & 7) << 3;
    u16 tmp[8];
#pragma unroll
    for (int j = 0; j < 8; ++j) tmp[j] = tile[col + j][t];
    *(uint4*)&dst[((size_t)(b * T_ + tb + t)) * C_ + hh * 64 + col] = *(uint4*)tmp;
  }
}

// ---------------------------------------------------------------- attention
// Zero-LDS, zero-barrier flash attention (see round-3 notes).
__global__ __launch_bounds__(512, 2) void attn_fwd2(
    const u16* __restrict__ Q, const u16* __restrict__ K,
    const u16* __restrict__ Vt, u16* __restrict__ Ot)
{
  const int b = blockIdx.x;                        // 256 blocks
  const int bh = (b & 7) * 4 + ((b >> 3) & 3);     // 4 bh per XCD (b%8)
  const int g  = b >> 5;                           // 0..7
  const int tid = threadIdx.x;
  const int w = tid >> 6, lane = tid & 63;
  const int l31 = lane & 31, hi = lane >> 5;
  const int qt = (w < 4) ? (g * 4 + w) : (63 - (g * 4 + (w - 4)));
  const int q0 = qt * 32;
  const int nt = qt + 1;                           // causal: tiles 0..qt

  bf16v8 qf[4];
  {
    const u16* qp = Q + ((size_t)bh * T_ + q0 + l31) * 64 + hi * 8;
    qf[0] = *(const bf16v8*)(qp);
    qf[1] = *(const bf16v8*)(qp + 16);
    qf[2] = *(const bf16v8*)(qp + 32);
    qf[3] = *(const bf16v8*)(qp + 48);
  }

  float m2 = -1e30f, lsum = 0.f;                   // log2-domain running max / sum
  f32x16 oacc0 = {}, oacc1 = {};                   // O^T d-blocks 0..31 / 32..63

  const u16* kbase = K + ((size_t)bh * T_ + l31) * 64 + hi * 8;
  const u16* vbase = Vt + ((size_t)bh * 64 + l31) * T_ + hi * 8;

  auto loadKV = [&](bf16v8 (&kf)[4], bf16v8 (&vf)[4], int t) {
    const u16* kp = kbase + (size_t)t * (32 * 64);
    kf[0] = *(const bf16v8*)(kp);
    kf[1] = *(const bf16v8*)(kp + 16);
    kf[2] = *(const bf16v8*)(kp + 32);
    kf[3] = *(const bf16v8*)(kp + 48);
    const u16* vp = vbase + t * 32;
    vf[0] = *(const bf16v8*)(vp);
    vf[1] = *(const bf16v8*)(vp + 16);
    vf[2] = *(const bf16v8*)(vp + (size_t)32 * T_);
    vf[3] = *(const bf16v8*)(vp + (size_t)32 * T_ + 16);
  };

  auto step = [&](const bf16v8 (&kf)[4], const bf16v8 (&vf)[4], bool diag) {
    f32x16 s = {};
    s = MFMA32(kf[0], qf[0], s);
    s = MFMA32(kf[1], qf[1], s);
    s = MFMA32(kf[2], qf[2], s);
    s = MFMA32(kf[3], qf[3], s);
    if (diag) {
#pragma unroll
      for (int r = 0; r < 16; ++r) {
        const int kl = (r & 3) + 8 * (r >> 2) + 4 * hi;
        if (kl > l31) s[r] = -1e30f;
      }
    }
    float pmax = s[0];
#pragma unroll
    for (int r = 1; r < 16; ++r) pmax = fmaxf(pmax, s[r]);
    pmax = fmaxf(pmax, __shfl_xor(pmax, 32));
    if (!__all(pmax <= m2 + 11.5416f)) {           // defer-max THR = 8*log2e
      const float mnew = fmaxf(m2, pmax);
      const float rs = __builtin_amdgcn_exp2f(m2 - mnew);
      lsum *= rs;
#pragma unroll
      for (int r = 0; r < 16; ++r) { oacc0[r] *= rs; oacc1[r] *= rs; }
      m2 = mnew;
    }
    float p[16]; float ts = 0.f;
#pragma unroll
    for (int r = 0; r < 16; ++r) {
      p[r] = __builtin_amdgcn_exp2f(s[r] - m2);
      ts += p[r];
    }
    ts += __shfl_xor(ts, 32);
    lsum += ts;
    uint32_t o[8];
#pragma unroll
    for (int j = 0; j < 8; ++j) {
      const int r0 = 4 * (j >> 1) + 2 * (j & 1);
      uint32_t d;
      asm("v_cvt_pk_bf16_f32 %0, %1, %2" : "=v"(d) : "v"(p[r0]), "v"(p[r0 + 1]));
      o[j] = d;
    }
    uint32_t po[8];
#pragma unroll
    for (int j = 0; j < 8; ++j) po[j] = __shfl_xor(o[j], 32);
#pragma unroll
    for (int kg = 0; kg < 2; ++kg) {
      u32x4 fr;
      fr.x = hi ? po[4 * kg + 2] : o[4 * kg + 0];
      fr.y = hi ? po[4 * kg + 3] : o[4 * kg + 1];
      fr.z = hi ? o[4 * kg + 2] : po[4 * kg + 0];
      fr.w = hi ? o[4 * kg + 3] : po[4 * kg + 1];
      const bf16v8 pf = __builtin_bit_cast(bf16v8, fr);
      oacc0 = MFMA32(vf[kg], pf, oacc0);
      oacc1 = MFMA32(vf[2 + kg], pf, oacc1);
    }
  };

  bf16v8 kA[4], vA[4], kB[4], vB[4];
  loadKV(kA, vA, 0);
  int t = 0;
  while (true) {
    if (t + 1 < nt) loadKV(kB, vB, t + 1);
    step(kA, vA, t == nt - 1);
    ++t; if (t >= nt) break;
    if (t + 1 < nt) loadKV(kA, vA, t + 1);
    step(kB, vB, t == nt - 1);
    ++t; if (t >= nt) break;
  }

  const float inv = 1.f / lsum;
  u16* obase = Ot + ((size_t)bh * 64) * T_ + q0 + l31;
#pragma unroll
  for (int r = 0; r < 16; ++r) {
    const int d0 = (r & 3) + 8 * (r >> 2) + 4 * hi;
    obase[(size_t)d0 * T_]        = f2bf(oacc0[r] * inv);
    obase[(size_t)(d0 + 32) * T_] = f2bf(oacc1[r] * inv);
  }
}

// ---------------------------------------------------------------- launch
extern "C" void kernel_launch(void* const* d_in, const int* in_sizes, int n_in,
                              void* d_out, int out_size, void* d_ws, size_t ws_size,
                              hipStream_t stream) {
  const float* x    = (const float*)d_in[0];
  const float* cosT = (const float*)d_in[1];
  const float* sinT = (const float*)d_in[2];
  // d_in[3] = mask (causal by construction, unused), d_in[4] = n_heads (=16)
  const float* Wq = (const float*)d_in[5];
  const float* Wk = (const float*)d_in[6];
  const float* Wv = (const float*)d_in[7];
  const float* Wo = (const float*)d_in[8];
  float* out = (float*)d_out;

  // workspace layout (48 MB total)
  char* ws = (char*)d_ws;
  u16* xb   = (u16*)(ws);                    // bf16 x; reused as aoutT after gemm1
  u16* wqkv = (u16*)(ws + 8388608);          // [Wq;Wk;Wv] bf16
  u16* wo   = (u16*)(ws + 14680064);         // Wo bf16
  u16* q    = (u16*)(ws + 16777216);         // (B,H,T,64) bf16, roped+scaled; reused as aout
  u16* k    = (u16*)(ws + 25165824);         // (B,H,T,64) bf16, roped
  u16* v    = (u16*)(ws + 33554432);         // (B,H,T,64) bf16
  u16* vt   = (u16*)(ws + 41943040);         // (B,H,64,T) bf16
  u16* aoutT = xb;                           // attention output^T (BH,64,T)
  u16* aout  = q;                            // transposed back (B,T,C)

  cvt_f32_bf16<<<4096, 256, 0, stream>>>(x, xb, BT * C_);
  cvt_weights<<<4096, 256, 0, stream>>>(Wq, Wk, Wv, Wo, wqkv, wo);

  gemm_qkv256<<<192, 512, 0, stream>>>(xb, wqkv, q, k, v, cosT, sinT);
  transpose_v<<<1024, 256, 0, stream>>>(v, vt);
  attn_fwd2<<<256, 512, 0, stream>>>(q, k, vt, aoutT);
  transpose_o<<<1024, 256, 0, stream>>>(aoutT, aout);
  gemm_bt<0, 1024><<<dim3(8, 32), 256, 0, stream>>>(aout, wo, out);
}

// Round 5
// 164.723 us; speedup vs baseline: 1.4302x; 1.0559x over previous
//
#include <hip/hip_runtime.h>
#include <stdint.h>

// Shapes are fixed by the reference: B=2, T=2048, C=1024, H=16, Dh=64.
#define B_   2
#define T_   2048
#define C_   1024
#define H_   16
#define BT   4096      // B_*T_
#define KDIM 1024      // inner dim of all projections

typedef unsigned short u16;
typedef __attribute__((ext_vector_type(8))) __bf16 bf16v8;   // 4 VGPR MFMA operand
typedef __attribute__((ext_vector_type(4))) float f32x4;     // 16x16 accumulator
typedef __attribute__((ext_vector_type(16))) float f32x16;   // 32x32 accumulator
typedef __attribute__((ext_vector_type(4))) unsigned int u32x4;

#define MFMA16(a, b, c) __builtin_amdgcn_mfma_f32_16x16x32_bf16((a), (b), (c), 0, 0, 0)
#define MFMA32(a, b, c) __builtin_amdgcn_mfma_f32_32x32x16_bf16((a), (b), (c), 0, 0, 0)

#define BARRIER() do { asm volatile("" ::: "memory"); \
                       __builtin_amdgcn_s_barrier();  \
                       asm volatile("" ::: "memory"); } while (0)

__device__ __forceinline__ u16 f2bf(float f) {
  __bf16 h = (__bf16)f;                       // native v_cvt (RNE)
  union { __bf16 h; u16 u; } v; v.h = h;
  return v.u;
}

// async global->LDS, 16B per lane; LDS dest is wave-uniform base + lane*16
__device__ __forceinline__ void gload16(const void* g, void* l) {
  __builtin_amdgcn_global_load_lds((__attribute__((address_space(1))) void*)g,
                                   (__attribute__((address_space(3))) void*)l,
                                   16, 0, 0);
}

// ---------------------------------------------------------------- fp32->bf16
__global__ __launch_bounds__(256) void cvt_f32_bf16(const float* __restrict__ in,
                                                    u16* __restrict__ out, int n) {
  int i = (blockIdx.x * 256 + threadIdx.x) * 4;
  if (i + 3 < n) {
    float4 v = *(const float4*)(in + i);
    ushort4 o;
    o.x = f2bf(v.x); o.y = f2bf(v.y); o.z = f2bf(v.z); o.w = f2bf(v.w);
    *(ushort4*)(out + i) = o;
  }
}

// all four 1024x1024 weight matrices in one launch
__global__ __launch_bounds__(256) void cvt_weights(
    const float* __restrict__ wq, const float* __restrict__ wk,
    const float* __restrict__ wv, const float* __restrict__ wo,
    u16* __restrict__ qkv_dst, u16* __restrict__ o_dst) {
  const int bid = blockIdx.x;          // 0..4095
  const int sel = bid >> 10;
  const float* src = (sel == 0) ? wq : (sel == 1) ? wk : (sel == 2) ? wv : wo;
  u16* dst = (sel < 3) ? (qkv_dst + sel * 1048576) : o_dst;
  const int i = ((bid & 1023) * 256 + threadIdx.x) * 4;
  float4 v = *(const float4*)(src + i);
  ushort4 o;
  o.x = f2bf(v.x); o.y = f2bf(v.y); o.z = f2bf(v.z); o.w = f2bf(v.w);
  *(ushort4*)(dst + i) = o;
}

// ---------------------------------------------------------------- GEMM 128x128
// C[M=4096, N=NN] = A[M,K=1024] * Bm[NN,K]^T.  BK=64, 4 waves (2x2), each wave
// a 64x64 quadrant (4x4 frags). 64 KiB double-buffered swizzled LDS -> 2
// blocks/CU co-resident (async overlap across blocks). Counted vmcnt(8): the
// next tile's 8 global_load_lds stay in flight across the barrier; never
// drained to 0 in the main loop. Bijective XCD block swizzle.
// EPI=0: fp32 C.  EPI=1: QKV fused RoPE + scatter (q pre-scaled 0.125*log2e).
template<int EPI, int NN>
__global__ __launch_bounds__(256, 2) void gemm128(
    const u16* __restrict__ A, const u16* __restrict__ Bm,
    float* __restrict__ Cf,
    u16* __restrict__ qo, u16* __restrict__ ko, u16* __restrict__ vo,
    const float* __restrict__ cosT, const float* __restrict__ sinT)
{
  __shared__ __align__(16) u16 As[2][128 * 64];   // 32 KiB
  __shared__ __align__(16) u16 Bs[2][128 * 64];   // 32 KiB
  const int tid = threadIdx.x;
  const int lane = tid & 63;
  const int w = tid >> 6;
  const int wm = w >> 1, wn = w & 1;
  const int lmod = lane & 15, ldiv = lane >> 4;

  const int nbx = NN / 128;
  const int nwg = nbx * (BT / 128);               // 768 or 256: %8 == 0
  const int swz = (blockIdx.x & 7) * (nwg >> 3) + (blockIdx.x >> 3);
  const int bx = swz % nbx, by = swz / nbx;
  const int row0 = by * 128, col0 = bx * 128;

  // staging: 128B rows, 8 threads/row, 4 chunks of 32 rows per matrix;
  // source col pre-XOR-swizzled by ((row&7)<<4)  (rule #21: swizzle source+read)
  const int srow = tid >> 3;                      // 0..31
  const int sswz = ((tid & 7) * 16) ^ ((srow & 7) << 4);
  const char* Abase = (const char*)A + (size_t)(row0 + srow) * (KDIM * 2) + sswz;
  const char* Bbase = (const char*)Bm + (size_t)(col0 + srow) * (KDIM * 2) + sswz;
  const int ldst = (tid & 192) * 16;              // wave-uniform LDS sub-base

  auto stage = [&](int buf, int t) {
    const int kb = t * 128;                       // K-tile byte offset in row
#pragma unroll
    for (int c = 0; c < 4; ++c)
      gload16(Abase + (size_t)c * 32 * (KDIM * 2) + kb,
              (char*)As[buf] + c * 4096 + ldst);
#pragma unroll
    for (int c = 0; c < 4; ++c)
      gload16(Bbase + (size_t)c * 32 * (KDIM * 2) + kb,
              (char*)Bs[buf] + c * 4096 + ldst);
  };

  f32x4 acc[4][4] = {};
  stage(0, 0);

  for (int t = 0; t < KDIM / 64; ++t) {
    const int cur = t & 1;
    BARRIER();                                    // all waves done reading buf[cur^1]
    if (t + 1 < KDIM / 64) {
      stage(cur ^ 1, t + 1);                      // 8 loads for t+1 in flight
      asm volatile("s_waitcnt vmcnt(8)" ::: "memory");   // tile t landed
    } else {
      asm volatile("s_waitcnt vmcnt(0)" ::: "memory");
    }
    BARRIER();                                    // cross-wave: tile t visible

    bf16v8 af[4][2], bfr[4][2];
#pragma unroll
    for (int mf = 0; mf < 4; ++mf) {
      const int rr = wm * 64 + mf * 16 + lmod;
#pragma unroll
      for (int kc = 0; kc < 2; ++kc)
        af[mf][kc] = *(const bf16v8*)((const char*)As[cur] + rr * 128 +
                          ((kc * 64 + ldiv * 16) ^ ((rr & 7) << 4)));
    }
#pragma unroll
    for (int nf = 0; nf < 4; ++nf) {
      const int rr = wn * 64 + nf * 16 + lmod;
#pragma unroll
      for (int kc = 0; kc < 2; ++kc)
        bfr[nf][kc] = *(const bf16v8*)((const char*)Bs[cur] + rr * 128 +
                          ((kc * 64 + ldiv * 16) ^ ((rr & 7) << 4)));
    }
#pragma unroll
    for (int kc = 0; kc < 2; ++kc)
#pragma unroll
      for (int mf = 0; mf < 4; ++mf)
#pragma unroll
        for (int nf = 0; nf < 4; ++nf)
          acc[mf][nf] = MFMA16(af[mf][kc], bfr[nf][kc], acc[mf][nf]);
  }

  if (EPI == 0) {
#pragma unroll
    for (int mf = 0; mf < 4; ++mf) {
      const int mbase = row0 + wm * 64 + mf * 16 + ldiv * 4;
#pragma unroll
      for (int nf = 0; nf < 4; ++nf) {
        const int n = col0 + wn * 64 + nf * 16 + lmod;
#pragma unroll
        for (int r = 0; r < 4; ++r)
          Cf[(size_t)(mbase + r) * NN + n] = acc[mf][nf][r];
      }
    }
  } else {
    // wave's 64-col block is head-aligned; RoPE pair (d, d+-32) = (nf, nf+-2)
    const int nb = col0 + wn * 64;
    const int proj = nb >> 10;            // 0=q 1=k 2=v
    const int hh = (nb & 1023) >> 6;      // head
    u16* dst = (proj == 0) ? qo : (proj == 1) ? ko : vo;
#pragma unroll
    for (int mf = 0; mf < 4; ++mf) {
#pragma unroll
      for (int r = 0; r < 4; ++r) {
        const int m = row0 + wm * 64 + mf * 16 + ldiv * 4 + r;
        const int b = m >> 11, t = m & 2047;
        u16* drow = dst + ((size_t)(b * H_ + hh) * T_ + t) * 64;
#pragma unroll
        for (int nf = 0; nf < 4; ++nf) {
          const int d = nf * 16 + lmod;
          float val = acc[mf][nf][r];
          if (proj < 2) {
            const float cs = cosT[t * 64 + d];
            const float sn = sinT[t * 64 + d];
            const float other = (nf < 2) ? acc[mf][nf + 2][r] : acc[mf][nf - 2][r];
            val = (nf < 2) ? (val * cs - other * sn) : (val * cs + other * sn);
            if (proj == 0) val *= 0.18033688011112042f;  // 0.125 * log2(e)
          }
          drow[d] = f2bf(val);
        }
      }
    }
  }
}

// ---------------------------------------------------------------- V -> V^T
// v (BH, T, 64) -> vt (BH, 64, T)
__global__ __launch_bounds__(256) void transpose_v(const u16* __restrict__ v,
                                                   u16* __restrict__ vt) {
  __shared__ __align__(16) u16 tile[64][72];
  const int bh = blockIdx.x >> 5;
  const int tb = (blockIdx.x & 31) << 6;
  const int tid = threadIdx.x;
#pragma unroll
  for (int c = 0; c < 2; ++c) {
    const int idx = c * 256 + tid;
    const int r = idx >> 3, col = (idx & 7) << 3;
    *(uint4*)&tile[r][col] = *(const uint4*)&v[((size_t)bh * T_ + tb + r) * 64 + col];
  }
  __syncthreads();
#pragma unroll
  for (int c = 0; c < 2; ++c) {
    const int idx = c * 256 + tid;
    const int d = idx >> 3, col = (idx & 7) << 3;
    u16 tmp[8];
#pragma unroll
    for (int j = 0; j < 8; ++j) tmp[j] = tile[col + j][d];
    *(uint4*)&vt[((size_t)bh * 64 + d) * T_ + tb + col] = *(uint4*)tmp;
  }
}

// ---------------------------------------------------------------- O^T -> O
__global__ __launch_bounds__(256) void transpose_o(const u16* __restrict__ src,
                                                   u16* __restrict__ dst) {
  __shared__ __align__(16) u16 tile[64][72];
  const int bh = blockIdx.x >> 5;
  const int tb = (blockIdx.x & 31) << 6;
  const int tid = threadIdx.x;
#pragma unroll
  for (int c = 0; c < 2; ++c) {
    const int idx = c * 256 + tid;
    const int d = idx >> 3, col = (idx & 7) << 3;       // [d][t]
    *(uint4*)&tile[d][col] = *(const uint4*)&src[((size_t)bh * 64 + d) * T_ + tb + col];
  }
  __syncthreads();
  const int b = bh >> 4, hh = bh & 15;
#pragma unroll
  for (int c = 0; c < 2; ++c) {
    const int idx = c * 256 + tid;
    const int t = idx >> 3, col = (idx & 7) << 3;
    u16 tmp[8];
#pragma unroll
    for (int j = 0; j < 8; ++j) tmp[j] = tile[col + j][t];
    *(uint4*)&dst[((size_t)(b * T_ + tb + t)) * C_ + hh * 64 + col] = *(uint4*)tmp;
  }
}

// ---------------------------------------------------------------- attention
// Zero-LDS, zero-barrier flash attention (see round-3 notes).
__global__ __launch_bounds__(512, 2) void attn_fwd2(
    const u16* __restrict__ Q, const u16* __restrict__ K,
    const u16* __restrict__ Vt, u16* __restrict__ Ot)
{
  const int b = blockIdx.x;                        // 256 blocks
  const int bh = (b & 7) * 4 + ((b >> 3) & 3);     // 4 bh per XCD (b%8)
  const int g  = b >> 5;                           // 0..7
  const int tid = threadIdx.x;
  const int w = tid >> 6, lane = tid & 63;
  const int l31 = lane & 31, hi = lane >> 5;
  const int qt = (w < 4) ? (g * 4 + w) : (63 - (g * 4 + (w - 4)));
  const int q0 = qt * 32;
  const int nt = qt + 1;                           // causal: tiles 0..qt

  bf16v8 qf[4];
  {
    const u16* qp = Q + ((size_t)bh * T_ + q0 + l31) * 64 + hi * 8;
    qf[0] = *(const bf16v8*)(qp);
    qf[1] = *(const bf16v8*)(qp + 16);
    qf[2] = *(const bf16v8*)(qp + 32);
    qf[3] = *(const bf16v8*)(qp + 48);
  }

  float m2 = -1e30f, lsum = 0.f;                   // log2-domain running max / sum
  f32x16 oacc0 = {}, oacc1 = {};                   // O^T d-blocks 0..31 / 32..63

  const u16* kbase = K + ((size_t)bh * T_ + l31) * 64 + hi * 8;
  const u16* vbase = Vt + ((size_t)bh * 64 + l31) * T_ + hi * 8;

  auto loadKV = [&](bf16v8 (&kf)[4], bf16v8 (&vf)[4], int t) {
    const u16* kp = kbase + (size_t)t * (32 * 64);
    kf[0] = *(const bf16v8*)(kp);
    kf[1] = *(const bf16v8*)(kp + 16);
    kf[2] = *(const bf16v8*)(kp + 32);
    kf[3] = *(const bf16v8*)(kp + 48);
    const u16* vp = vbase + t * 32;
    vf[0] = *(const bf16v8*)(vp);
    vf[1] = *(const bf16v8*)(vp + 16);
    vf[2] = *(const bf16v8*)(vp + (size_t)32 * T_);
    vf[3] = *(const bf16v8*)(vp + (size_t)32 * T_ + 16);
  };

  auto step = [&](const bf16v8 (&kf)[4], const bf16v8 (&vf)[4], bool diag) {
    f32x16 s = {};
    s = MFMA32(kf[0], qf[0], s);
    s = MFMA32(kf[1], qf[1], s);
    s = MFMA32(kf[2], qf[2], s);
    s = MFMA32(kf[3], qf[3], s);
    if (diag) {
#pragma unroll
      for (int r = 0; r < 16; ++r) {
        const int kl = (r & 3) + 8 * (r >> 2) + 4 * hi;
        if (kl > l31) s[r] = -1e30f;
      }
    }
    float pmax = s[0];
#pragma unroll
    for (int r = 1; r < 16; ++r) pmax = fmaxf(pmax, s[r]);
    pmax = fmaxf(pmax, __shfl_xor(pmax, 32));
    if (!__all(pmax <= m2 + 11.5416f)) {           // defer-max THR = 8*log2e
      const float mnew = fmaxf(m2, pmax);
      const float rs = __builtin_amdgcn_exp2f(m2 - mnew);
      lsum *= rs;
#pragma unroll
      for (int r = 0; r < 16; ++r) { oacc0[r] *= rs; oacc1[r] *= rs; }
      m2 = mnew;
    }
    float p[16]; float ts = 0.f;
#pragma unroll
    for (int r = 0; r < 16; ++r) {
      p[r] = __builtin_amdgcn_exp2f(s[r] - m2);
      ts += p[r];
    }
    ts += __shfl_xor(ts, 32);
    lsum += ts;
    uint32_t o[8];
#pragma unroll
    for (int j = 0; j < 8; ++j) {
      const int r0 = 4 * (j >> 1) + 2 * (j & 1);
      uint32_t d;
      asm("v_cvt_pk_bf16_f32 %0, %1, %2" : "=v"(d) : "v"(p[r0]), "v"(p[r0 + 1]));
      o[j] = d;
    }
    uint32_t po[8];
#pragma unroll
    for (int j = 0; j < 8; ++j) po[j] = __shfl_xor(o[j], 32);
#pragma unroll
    for (int kg = 0; kg < 2; ++kg) {
      u32x4 fr;
      fr.x = hi ? po[4 * kg + 2] : o[4 * kg + 0];
      fr.y = hi ? po[4 * kg + 3] : o[4 * kg + 1];
      fr.z = hi ? o[4 * kg + 2] : po[4 * kg + 0];
      fr.w = hi ? o[4 * kg + 3] : po[4 * kg + 1];
      const bf16v8 pf = __builtin_bit_cast(bf16v8, fr);
      oacc0 = MFMA32(vf[kg], pf, oacc0);
      oacc1 = MFMA32(vf[2 + kg], pf, oacc1);
    }
  };

  bf16v8 kA[4], vA[4], kB[4], vB[4];
  loadKV(kA, vA, 0);
  int t = 0;
  while (true) {
    if (t + 1 < nt) loadKV(kB, vB, t + 1);
    step(kA, vA, t == nt - 1);
    ++t; if (t >= nt) break;
    if (t + 1 < nt) loadKV(kA, vA, t + 1);
    step(kB, vB, t == nt - 1);
    ++t; if (t >= nt) break;
  }

  const float inv = 1.f / lsum;
  u16* obase = Ot + ((size_t)bh * 64) * T_ + q0 + l31;
#pragma unroll
  for (int r = 0; r < 16; ++r) {
    const int d0 = (r & 3) + 8 * (r >> 2) + 4 * hi;
    obase[(size_t)d0 * T_]        = f2bf(oacc0[r] * inv);
    obase[(size_t)(d0 + 32) * T_] = f2bf(oacc1[r] * inv);
  }
}

// ---------------------------------------------------------------- launch
extern "C" void kernel_launch(void* const* d_in, const int* in_sizes, int n_in,
                              void* d_out, int out_size, void* d_ws, size_t ws_size,
                              hipStream_t stream) {
  const float* x    = (const float*)d_in[0];
  const float* cosT = (const float*)d_in[1];
  const float* sinT = (const float*)d_in[2];
  // d_in[3] = mask (causal by construction, unused), d_in[4] = n_heads (=16)
  const float* Wq = (const float*)d_in[5];
  const float* Wk = (const float*)d_in[6];
  const float* Wv = (const float*)d_in[7];
  const float* Wo = (const float*)d_in[8];
  float* out = (float*)d_out;

  // workspace layout (48 MB total)
  char* ws = (char*)d_ws;
  u16* xb   = (u16*)(ws);                    // bf16 x; reused as aoutT after gemm1
  u16* wqkv = (u16*)(ws + 8388608);          // [Wq;Wk;Wv] bf16
  u16* wo   = (u16*)(ws + 14680064);         // Wo bf16
  u16* q    = (u16*)(ws + 16777216);         // (B,H,T,64) bf16, roped+scaled; reused as aout
  u16* k    = (u16*)(ws + 25165824);         // (B,H,T,64) bf16, roped
  u16* v    = (u16*)(ws + 33554432);         // (B,H,T,64) bf16
  u16* vt   = (u16*)(ws + 41943040);         // (B,H,64,T) bf16
  u16* aoutT = xb;                           // attention output^T (BH,64,T)
  u16* aout  = q;                            // transposed back (B,T,C)

  cvt_f32_bf16<<<4096, 256, 0, stream>>>(x, xb, BT * C_);
  cvt_weights<<<4096, 256, 0, stream>>>(Wq, Wk, Wv, Wo, wqkv, wo);

  gemm128<1, 3072><<<768, 256, 0, stream>>>(xb, wqkv, nullptr,
                                            q, k, v, cosT, sinT);
  transpose_v<<<1024, 256, 0, stream>>>(v, vt);
  attn_fwd2<<<256, 512, 0, stream>>>(q, k, vt, aoutT);
  transpose_o<<<1024, 256, 0, stream>>>(aoutT, aout);
  gemm128<0, 1024><<<256, 256, 0, stream>>>(aout, wo, out,
                                            nullptr, nullptr, nullptr,
                                            nullptr, nullptr);
}

// Round 6
// 151.247 us; speedup vs baseline: 1.5576x; 1.0891x over previous
//
#include <hip/hip_runtime.h>
#include <stdint.h>

// Shapes are fixed by the reference: B=2, T=2048, C=1024, H=16, Dh=64.
#define B_   2
#define T_   2048
#define C_   1024
#define H_   16
#define BT   4096      // B_*T_
#define KDIM 1024      // inner dim of all projections

typedef unsigned short u16;
typedef __attribute__((ext_vector_type(8))) __bf16 bf16v8;   // 4 VGPR MFMA operand
typedef __attribute__((ext_vector_type(4))) float f32x4;     // 16x16 accumulator
typedef __attribute__((ext_vector_type(16))) float f32x16;   // 32x32 accumulator
typedef __attribute__((ext_vector_type(4))) unsigned int u32x4;

#define MFMA16(a, b, c) __builtin_amdgcn_mfma_f32_16x16x32_bf16((a), (b), (c), 0, 0, 0)
#define MFMA32(a, b, c) __builtin_amdgcn_mfma_f32_32x32x16_bf16((a), (b), (c), 0, 0, 0)

#define BARRIER() do { asm volatile("" ::: "memory"); \
                       __builtin_amdgcn_s_barrier();  \
                       asm volatile("" ::: "memory"); } while (0)

__device__ __forceinline__ u16 f2bf(float f) {
  __bf16 h = (__bf16)f;                       // native v_cvt (RNE)
  union { __bf16 h; u16 u; } v; v.h = h;
  return v.u;
}

// async global->LDS, 16B per lane; LDS dest is wave-uniform base + lane*16
__device__ __forceinline__ void gload16(const void* g, void* l) {
  __builtin_amdgcn_global_load_lds((__attribute__((address_space(1))) void*)g,
                                   (__attribute__((address_space(3))) void*)l,
                                   16, 0, 0);
}

// ---------------------------------------------------------------- fp32->bf16
__global__ __launch_bounds__(256) void cvt_f32_bf16(const float* __restrict__ in,
                                                    u16* __restrict__ out, int n) {
  int i = (blockIdx.x * 256 + threadIdx.x) * 4;
  if (i + 3 < n) {
    float4 v = *(const float4*)(in + i);
    ushort4 o;
    o.x = f2bf(v.x); o.y = f2bf(v.y); o.z = f2bf(v.z); o.w = f2bf(v.w);
    *(ushort4*)(out + i) = o;
  }
}

// all four 1024x1024 weight matrices in one launch
__global__ __launch_bounds__(256) void cvt_weights(
    const float* __restrict__ wq, const float* __restrict__ wk,
    const float* __restrict__ wv, const float* __restrict__ wo,
    u16* __restrict__ qkv_dst, u16* __restrict__ o_dst) {
  const int bid = blockIdx.x;          // 0..4095
  const int sel = bid >> 10;
  const float* src = (sel == 0) ? wq : (sel == 1) ? wk : (sel == 2) ? wv : wo;
  u16* dst = (sel < 3) ? (qkv_dst + sel * 1048576) : o_dst;
  const int i = ((bid & 1023) * 256 + threadIdx.x) * 4;
  float4 v = *(const float4*)(src + i);
  ushort4 o;
  o.x = f2bf(v.x); o.y = f2bf(v.y); o.z = f2bf(v.z); o.w = f2bf(v.w);
  *(ushort4*)(dst + i) = o;
}

// ---------------------------------------------------------------- GEMM 128x128
// (unchanged from round 5; see notes there)
template<int EPI, int NN>
__global__ __launch_bounds__(256, 2) void gemm128(
    const u16* __restrict__ A, const u16* __restrict__ Bm,
    float* __restrict__ Cf,
    u16* __restrict__ qo, u16* __restrict__ ko, u16* __restrict__ vo,
    const float* __restrict__ cosT, const float* __restrict__ sinT)
{
  __shared__ __align__(16) u16 As[2][128 * 64];   // 32 KiB
  __shared__ __align__(16) u16 Bs[2][128 * 64];   // 32 KiB
  const int tid = threadIdx.x;
  const int lane = tid & 63;
  const int w = tid >> 6;
  const int wm = w >> 1, wn = w & 1;
  const int lmod = lane & 15, ldiv = lane >> 4;

  const int nbx = NN / 128;
  const int nwg = nbx * (BT / 128);               // 768 or 256: %8 == 0
  const int swz = (blockIdx.x & 7) * (nwg >> 3) + (blockIdx.x >> 3);
  const int bx = swz % nbx, by = swz / nbx;
  const int row0 = by * 128, col0 = bx * 128;

  const int srow = tid >> 3;                      // 0..31
  const int sswz = ((tid & 7) * 16) ^ ((srow & 7) << 4);
  const char* Abase = (const char*)A + (size_t)(row0 + srow) * (KDIM * 2) + sswz;
  const char* Bbase = (const char*)Bm + (size_t)(col0 + srow) * (KDIM * 2) + sswz;
  const int ldst = (tid & 192) * 16;              // wave-uniform LDS sub-base

  auto stage = [&](int buf, int t) {
    const int kb = t * 128;                       // K-tile byte offset in row
#pragma unroll
    for (int c = 0; c < 4; ++c)
      gload16(Abase + (size_t)c * 32 * (KDIM * 2) + kb,
              (char*)As[buf] + c * 4096 + ldst);
#pragma unroll
    for (int c = 0; c < 4; ++c)
      gload16(Bbase + (size_t)c * 32 * (KDIM * 2) + kb,
              (char*)Bs[buf] + c * 4096 + ldst);
  };

  f32x4 acc[4][4] = {};
  stage(0, 0);

  for (int t = 0; t < KDIM / 64; ++t) {
    const int cur = t & 1;
    BARRIER();                                    // all waves done reading buf[cur^1]
    if (t + 1 < KDIM / 64) {
      stage(cur ^ 1, t + 1);                      // 8 loads for t+1 in flight
      asm volatile("s_waitcnt vmcnt(8)" ::: "memory");   // tile t landed
    } else {
      asm volatile("s_waitcnt vmcnt(0)" ::: "memory");
    }
    BARRIER();                                    // cross-wave: tile t visible

    bf16v8 af[4][2], bfr[4][2];
#pragma unroll
    for (int mf = 0; mf < 4; ++mf) {
      const int rr = wm * 64 + mf * 16 + lmod;
#pragma unroll
      for (int kc = 0; kc < 2; ++kc)
        af[mf][kc] = *(const bf16v8*)((const char*)As[cur] + rr * 128 +
                          ((kc * 64 + ldiv * 16) ^ ((rr & 7) << 4)));
    }
#pragma unroll
    for (int nf = 0; nf < 4; ++nf) {
      const int rr = wn * 64 + nf * 16 + lmod;
#pragma unroll
      for (int kc = 0; kc < 2; ++kc)
        bfr[nf][kc] = *(const bf16v8*)((const char*)Bs[cur] + rr * 128 +
                          ((kc * 64 + ldiv * 16) ^ ((rr & 7) << 4)));
    }
#pragma unroll
    for (int kc = 0; kc < 2; ++kc)
#pragma unroll
      for (int mf = 0; mf < 4; ++mf)
#pragma unroll
        for (int nf = 0; nf < 4; ++nf)
          acc[mf][nf] = MFMA16(af[mf][kc], bfr[nf][kc], acc[mf][nf]);
  }

  if (EPI == 0) {
#pragma unroll
    for (int mf = 0; mf < 4; ++mf) {
      const int mbase = row0 + wm * 64 + mf * 16 + ldiv * 4;
#pragma unroll
      for (int nf = 0; nf < 4; ++nf) {
        const int n = col0 + wn * 64 + nf * 16 + lmod;
#pragma unroll
        for (int r = 0; r < 4; ++r)
          Cf[(size_t)(mbase + r) * NN + n] = acc[mf][nf][r];
      }
    }
  } else {
    // wave's 64-col block is head-aligned; RoPE pair (d, d+-32) = (nf, nf+-2)
    const int nb = col0 + wn * 64;
    const int proj = nb >> 10;            // 0=q 1=k 2=v
    const int hh = (nb & 1023) >> 6;      // head
    u16* dst = (proj == 0) ? qo : (proj == 1) ? ko : vo;
#pragma unroll
    for (int mf = 0; mf < 4; ++mf) {
#pragma unroll
      for (int r = 0; r < 4; ++r) {
        const int m = row0 + wm * 64 + mf * 16 + ldiv * 4 + r;
        const int b = m >> 11, t = m & 2047;
        u16* drow = dst + ((size_t)(b * H_ + hh) * T_ + t) * 64;
#pragma unroll
        for (int nf = 0; nf < 4; ++nf) {
          const int d = nf * 16 + lmod;
          float val = acc[mf][nf][r];
          if (proj < 2) {
            const float cs = cosT[t * 64 + d];
            const float sn = sinT[t * 64 + d];
            const float other = (nf < 2) ? acc[mf][nf + 2][r] : acc[mf][nf - 2][r];
            val = (nf < 2) ? (val * cs - other * sn) : (val * cs + other * sn);
            if (proj == 0) val *= 0.18033688011112042f;  // 0.125 * log2(e)
          }
          drow[d] = f2bf(val);
        }
      }
    }
  }
}

// ---------------------------------------------------------------- V -> V^T
// v (BH, T, 64) -> vt (BH, 64, T)
__global__ __launch_bounds__(256) void transpose_v(const u16* __restrict__ v,
                                                   u16* __restrict__ vt) {
  __shared__ __align__(16) u16 tile[64][72];
  const int bh = blockIdx.x >> 5;
  const int tb = (blockIdx.x & 31) << 6;
  const int tid = threadIdx.x;
#pragma unroll
  for (int c = 0; c < 2; ++c) {
    const int idx = c * 256 + tid;
    const int r = idx >> 3, col = (idx & 7) << 3;
    *(uint4*)&tile[r][col] = *(const uint4*)&v[((size_t)bh * T_ + tb + r) * 64 + col];
  }
  __syncthreads();
#pragma unroll
  for (int c = 0; c < 2; ++c) {
    const int idx = c * 256 + tid;
    const int d = idx >> 3, col = (idx & 7) << 3;
    u16 tmp[8];
#pragma unroll
    for (int j = 0; j < 8; ++j) tmp[j] = tile[col + j][d];
    *(uint4*)&vt[((size_t)bh * 64 + d) * T_ + tb + col] = *(uint4*)tmp;
  }
}

// ---------------------------------------------------------------- O^T -> O
__global__ __launch_bounds__(256) void transpose_o(const u16* __restrict__ src,
                                                   u16* __restrict__ dst) {
  __shared__ __align__(16) u16 tile[64][72];
  const int bh = blockIdx.x >> 5;
  const int tb = (blockIdx.x & 31) << 6;
  const int tid = threadIdx.x;
#pragma unroll
  for (int c = 0; c < 2; ++c) {
    const int idx = c * 256 + tid;
    const int d = idx >> 3, col = (idx & 7) << 3;       // [d][t]
    *(uint4*)&tile[d][col] = *(const uint4*)&src[((size_t)bh * 64 + d) * T_ + tb + col];
  }
  __syncthreads();
  const int b = bh >> 4, hh = bh & 15;
#pragma unroll
  for (int c = 0; c < 2; ++c) {
    const int idx = c * 256 + tid;
    const int t = idx >> 3, col = (idx & 7) << 3;
    u16 tmp[8];
#pragma unroll
    for (int j = 0; j < 8; ++j) tmp[j] = tile[col + j][t];
    *(uint4*)&dst[((size_t)(b * T_ + tb + t)) * C_ + hh * 64 + col] = *(uint4*)tmp;
  }
}

// ---------------------------------------------------------------- attention
// Block-cooperative flash attention (m214 shape). One block = 128 consecutive
// q-rows of one (b,h): 4 waves x 32 rows -> all waves share the causal range
// (no lockstep imbalance). K and V^T KVBLK=64 tiles staged once per block into
// XOR-swizzled double-buffered LDS (pre-swizzled global source, rule #21),
// counted vmcnt(4) prefetch. Per-wave math: swapped MFMA32 QK^T (S^T: q=lane,
// keys lane-local), exp2-domain in-register softmax, cvt_pk+shfl P pack,
// transposed O accumulation. Blocks dispatched as balanced heavy+light chunk
// pairs (cr, 15-cr): every CU gets exactly 34 tiles; 2 blocks/CU co-resident.
__global__ __launch_bounds__(256, 2) void attn_fwd3(
    const u16* __restrict__ Q, const u16* __restrict__ K,
    const u16* __restrict__ Vt, u16* __restrict__ Ot)
{
  __shared__ __align__(16) u16 Kl[2][64 * 64];    // 8 KiB per buffer
  __shared__ __align__(16) u16 Vl[2][64 * 64];
  // block decode: xcd-local bh, heavy/light chunk pairing
  const int xcd = blockIdx.x & 7;
  const int idx = blockIdx.x >> 3;          // 0..63
  const int h   = idx & 1;
  const int j   = idx >> 1;                 // 0..31
  const int bh  = xcd * 4 + (j & 3);
  const int cr  = j >> 2;                   // 0..7
  const int chunk = h ? (15 - cr) : cr;     // q-chunk 0..15
  const int qb0 = chunk * 128;
  const int nblk = 2 * chunk + 2;           // 64-key tiles in causal range

  const int tid = threadIdx.x, lane = tid & 63, w = tid >> 6;
  const int l31 = lane & 31, hi = lane >> 5;
  const int qrow = qb0 + w * 32;

  // Q B-fragments (whole kernel): lane holds Q[qrow+l31][c*16+hi*8+j]
  bf16v8 qf[4];
  {
    const u16* qp = Q + ((size_t)bh * T_ + qrow + l31) * 64 + hi * 8;
    qf[0] = *(const bf16v8*)(qp);
    qf[1] = *(const bf16v8*)(qp + 16);
    qf[2] = *(const bf16v8*)(qp + 32);
    qf[3] = *(const bf16v8*)(qp + 48);
  }

  float m2 = -1e30f, lsum = 0.f;            // log2-domain running max / sum
  f32x16 oacc0 = {}, oacc1 = {};            // O^T d-blocks 0..31 / 32..63

  // staging bases (256 threads; 4 gload16/thread/tile: 2 K rounds + 2 V rounds)
  const int srow = (tid >> 3) & 63;         // row covered by this thread's slot
  const int scolb = (tid & 7) * 16;         // 16B col within 128B row
  const int sswz = scolb ^ ((srow & 7) << 4);
  const int ldst = (tid & 192) * 16;        // wave-uniform LDS sub-base

  auto stage = [&](int buf, int t) {
    const int s0 = t << 6;
#pragma unroll
    for (int c = 0; c < 2; ++c) {
      const int row = (c * 256 + tid) >> 3; // 0..63 over the two rounds
      const int sw = scolb ^ ((row & 7) << 4);
      gload16((const char*)(K + ((size_t)bh * T_ + s0 + row) * 64) + sw,
              (char*)Kl[buf] + c * 4096 + ldst);
    }
#pragma unroll
    for (int c = 0; c < 2; ++c) {
      const int row = (c * 256 + tid) >> 3; // d = 0..63
      const int sw = scolb ^ ((row & 7) << 4);
      gload16((const char*)(Vt + ((size_t)(bh * 64 + row)) * T_ + s0) + sw,
              (char*)Vl[buf] + c * 4096 + ldst);
    }
  };
  (void)srow; (void)sswz;

  // one 32-key substep from LDS buffer cur
  auto substep = [&](int cur, int sub, int s0_sub) {
    // K fragments: A[row=key_local=l31][k=c*16+hi*8+j]
    bf16v8 kf[4], vf[4];
#pragma unroll
    for (int c = 0; c < 4; ++c) {
      const int row = sub * 32 + l31;
      kf[c] = *(const bf16v8*)((const char*)Kl[cur] + row * 128 +
                  ((c * 32 + hi * 16) ^ ((row & 7) << 4)));
    }
    // V^T fragments: A[row=d][k=key_local=kg*16+hi*8+j]
#pragma unroll
    for (int db = 0; db < 2; ++db)
#pragma unroll
      for (int kg = 0; kg < 2; ++kg) {
        const int row = db * 32 + l31;
        vf[db * 2 + kg] = *(const bf16v8*)((const char*)Vl[cur] + row * 128 +
                  ((sub * 64 + kg * 32 + hi * 16) ^ ((row & 7) << 4)));
      }
    f32x16 s = {};
    s = MFMA32(kf[0], qf[0], s);
    s = MFMA32(kf[1], qf[1], s);
    s = MFMA32(kf[2], qf[2], s);
    s = MFMA32(kf[3], qf[3], s);
    if (s0_sub + 31 > qrow) {               // diagonal substep: causal mask
#pragma unroll
      for (int r = 0; r < 16; ++r) {
        const int key = s0_sub + (r & 3) + 8 * (r >> 2) + 4 * hi;
        if (key > qrow + l31) s[r] = -1e30f;
      }
    }
    float pmax = s[0];
#pragma unroll
    for (int r = 1; r < 16; ++r) pmax = fmaxf(pmax, s[r]);
    pmax = fmaxf(pmax, __shfl_xor(pmax, 32));
    if (!__all(pmax <= m2 + 11.5416f)) {    // defer-max THR = 8*log2e
      const float mnew = fmaxf(m2, pmax);
      const float rs = __builtin_amdgcn_exp2f(m2 - mnew);
      lsum *= rs;
#pragma unroll
      for (int r = 0; r < 16; ++r) { oacc0[r] *= rs; oacc1[r] *= rs; }
      m2 = mnew;
    }
    float p[16]; float ts = 0.f;
#pragma unroll
    for (int r = 0; r < 16; ++r) {
      p[r] = __builtin_amdgcn_exp2f(s[r] - m2);
      ts += p[r];
    }
    ts += __shfl_xor(ts, 32);
    lsum += ts;
    uint32_t o[8];
#pragma unroll
    for (int jj = 0; jj < 8; ++jj) {
      const int r0 = 4 * (jj >> 1) + 2 * (jj & 1);
      uint32_t d;
      asm("v_cvt_pk_bf16_f32 %0, %1, %2" : "=v"(d) : "v"(p[r0]), "v"(p[r0 + 1]));
      o[jj] = d;
    }
    uint32_t po[8];
#pragma unroll
    for (int jj = 0; jj < 8; ++jj) po[jj] = __shfl_xor(o[jj], 32);
#pragma unroll
    for (int kg = 0; kg < 2; ++kg) {
      u32x4 fr;
      fr.x = hi ? po[4 * kg + 2] : o[4 * kg + 0];
      fr.y = hi ? po[4 * kg + 3] : o[4 * kg + 1];
      fr.z = hi ? o[4 * kg + 2] : po[4 * kg + 0];
      fr.w = hi ? o[4 * kg + 3] : po[4 * kg + 1];
      const bf16v8 pf = __builtin_bit_cast(bf16v8, fr);
      oacc0 = MFMA32(vf[kg], pf, oacc0);
      oacc1 = MFMA32(vf[2 + kg], pf, oacc1);
    }
  };

  stage(0, 0);
  for (int t = 0; t < nblk; ++t) {
    const int cur = t & 1;
    BARRIER();                              // waves done reading buf[cur^1]
    if (t + 1 < nblk) {
      stage(cur ^ 1, t + 1);                // 4 loads for t+1 stay in flight
      asm volatile("s_waitcnt vmcnt(4)" ::: "memory");   // tile t landed
    } else {
      asm volatile("s_waitcnt vmcnt(0)" ::: "memory");
    }
    BARRIER();                              // tile t visible to all waves
#pragma unroll
    for (int sub = 0; sub < 2; ++sub) {
      const int s0_sub = t * 64 + sub * 32;
      if (s0_sub <= qrow + 31) substep(cur, sub, s0_sub);
    }
  }

  const float inv = 1.f / lsum;
  u16* obase = Ot + ((size_t)bh * 64) * T_ + qrow + l31;
#pragma unroll
  for (int r = 0; r < 16; ++r) {
    const int d0 = (r & 3) + 8 * (r >> 2) + 4 * hi;
    obase[(size_t)d0 * T_]        = f2bf(oacc0[r] * inv);
    obase[(size_t)(d0 + 32) * T_] = f2bf(oacc1[r] * inv);
  }
}

// ---------------------------------------------------------------- launch
extern "C" void kernel_launch(void* const* d_in, const int* in_sizes, int n_in,
                              void* d_out, int out_size, void* d_ws, size_t ws_size,
                              hipStream_t stream) {
  const float* x    = (const float*)d_in[0];
  const float* cosT = (const float*)d_in[1];
  const float* sinT = (const float*)d_in[2];
  // d_in[3] = mask (causal by construction, unused), d_in[4] = n_heads (=16)
  const float* Wq = (const float*)d_in[5];
  const float* Wk = (const float*)d_in[6];
  const float* Wv = (const float*)d_in[7];
  const float* Wo = (const float*)d_in[8];
  float* out = (float*)d_out;

  // workspace layout (48 MB total)
  char* ws = (char*)d_ws;
  u16* xb   = (u16*)(ws);                    // bf16 x; reused as aoutT after gemm1
  u16* wqkv = (u16*)(ws + 8388608);          // [Wq;Wk;Wv] bf16
  u16* wo   = (u16*)(ws + 14680064);         // Wo bf16
  u16* q    = (u16*)(ws + 16777216);         // (B,H,T,64) bf16, roped+scaled; reused as aout
  u16* k    = (u16*)(ws + 25165824);         // (B,H,T,64) bf16, roped
  u16* v    = (u16*)(ws + 33554432);         // (B,H,T,64) bf16
  u16* vt   = (u16*)(ws + 41943040);         // (B,H,64,T) bf16
  u16* aoutT = xb;                           // attention output^T (BH,64,T)
  u16* aout  = q;                            // transposed back (B,T,C)

  cvt_f32_bf16<<<4096, 256, 0, stream>>>(x, xb, BT * C_);
  cvt_weights<<<4096, 256, 0, stream>>>(Wq, Wk, Wv, Wo, wqkv, wo);

  gemm128<1, 3072><<<768, 256, 0, stream>>>(xb, wqkv, nullptr,
                                            q, k, v, cosT, sinT);
  transpose_v<<<1024, 256, 0, stream>>>(v, vt);
  attn_fwd3<<<512, 256, 0, stream>>>(q, k, vt, aoutT);
  transpose_o<<<1024, 256, 0, stream>>>(aoutT, aout);
  gemm128<0, 1024><<<256, 256, 0, stream>>>(aout, wo, out,
                                            nullptr, nullptr, nullptr,
                                            nullptr, nullptr);
}